// Round 5
// baseline (1293.421 us; speedup 1.0000x reference)
//
#include <hip/hip_runtime.h>
#include <hip/hip_bf16.h>

#define N_NODES  60000
#define N_EDGES  240000
#define N_REL    4
#define N_GRAPHS 128
#define D_IN     768
#define D_H      256
#define N_LAYERS 6
#define M_PAD    60032            // 469 * 128 = 938 * 64
#define N_TOT    1280             // L0 out: 256 root + 4*256 msg; mid K: 1024 agg + 256 self

static inline int cdiv(int a, int b) { return (a + b - 1) / b; }

typedef __attribute__((ext_vector_type(8))) short short8;
typedef __attribute__((ext_vector_type(4))) float f32x4;

__device__ __forceinline__ float bf2f(unsigned short u) {
    union { unsigned int i; float f; } c; c.i = ((unsigned int)u) << 16; return c.f;
}
__device__ __forceinline__ float bflo(unsigned int u) {
    union { unsigned int i; float f; } c; c.i = u << 16; return c.f;
}
__device__ __forceinline__ float bfhi(unsigned int u) {
    union { unsigned int i; float f; } c; c.i = u & 0xffff0000u; return c.f;
}
__device__ __forceinline__ unsigned short f2bf(float f) {
    union { float f; unsigned int i; } c; c.f = f;
    unsigned int i = c.i;
    unsigned int r = (i + 0x7FFFu + ((i >> 16) & 1u)) >> 16;   // RNE
    return (unsigned short)r;
}

__device__ __forceinline__ void gload16(const void* g, void* l) {
    __builtin_amdgcn_global_load_lds((const __attribute__((address_space(1))) void*)g,
                                     (__attribute__((address_space(3))) void*)l, 16, 0, 0);
}

// ---------------------------------------------------------------------------
// Layer-0 GEMM (transform-first): A[M_PAD,768] bf16 @ Wt0[1280,768]^T.
// Double-buffered LDS; XCD-chunked tile remap (A row-panel L2 reuse).
// grid = 8 * 295 (15 tail blocks idle).
// ---------------------------------------------------------------------------
__global__ __launch_bounds__(512) void gemm_l0(
    const unsigned short* __restrict__ A,
    const unsigned short* __restrict__ Bt,
    const float* __restrict__ bias,
    unsigned short* __restrict__ out_root,
    unsigned short* __restrict__ out_msg,
    int K)
{
    __shared__ __align__(16) unsigned short S[2][(128 + 256) * 32];   // 2 x 24576 B

    const int bid  = blockIdx.x;
    const int xcd  = bid & 7;
    const int j    = bid >> 3;                       // 0..294
    const int nrow = (xcd < 5) ? 59 : 58;
    const int rbase = (xcd < 5) ? xcd * 59 : 295 + (xcd - 5) * 58;
    const int rr = j / 5, cc = j % 5;
    if (rr >= nrow) return;
    const int bm = (rbase + rr) * 128;
    const int bn = cc * 256;

    const int tid  = threadIdx.x;
    const int wave = tid >> 6, lane = tid & 63;
    const int wm = (wave & 1) * 64, wn = (wave >> 1) * 64;

    const int lr = lane >> 2;
    const int kg = ((lane & 3) ^ ((lr ^ (lr >> 2)) & 3)) * 8;   // swizzled k-chunk
    const unsigned short* gsrc[3];
    int ldoff[3];
    #pragma unroll
    for (int t = 0; t < 3; ++t) {
        int g = wave * 3 + t;
        if (g < 8) {
            gsrc[t] = A + (size_t)(bm + g * 16 + lr) * K + kg;
            ldoff[t] = g * 512;                       // As region: shorts 0..4095
        } else {
            gsrc[t] = Bt + (size_t)(bn + (g - 8) * 16 + lr) * K + kg;
            ldoff[t] = 4096 + (g - 8) * 512;          // Bs region: shorts 4096..12287
        }
    }

    f32x4 acc[4][4] = {};
    const int fr = lane & 15;
    const int qsw = (((lane >> 4) ^ fr ^ (fr >> 2)) & 3) * 8;

    const int nstep = K >> 5;                         // 24
    gload16(gsrc[0], S[0] + ldoff[0]);
    gload16(gsrc[1], S[0] + ldoff[1]);
    gload16(gsrc[2], S[0] + ldoff[2]);
    __syncthreads();                                  // slice 0 staged

    #pragma unroll 1
    for (int t = 0; t < nstep; ++t) {
        if (t + 1 < nstep) {                          // stage ahead into alt buffer
            unsigned short* nb = S[(t + 1) & 1];
            gload16(gsrc[0] + (t + 1) * 32, nb + ldoff[0]);
            gload16(gsrc[1] + (t + 1) * 32, nb + ldoff[1]);
            gload16(gsrc[2] + (t + 1) * 32, nb + ldoff[2]);
        }
        const unsigned short* cur = S[t & 1];
        short8 a[4], b[4];
        #pragma unroll
        for (int q = 0; q < 4; ++q) {
            a[q] = *(const short8*)&cur[(wm + q * 16 + fr) * 32 + qsw];
            b[q] = *(const short8*)&cur[4096 + (wn + q * 16 + fr) * 32 + qsw];
        }
        #pragma unroll
        for (int mt = 0; mt < 4; ++mt)
            #pragma unroll
            for (int nt = 0; nt < 4; ++nt)
                acc[mt][nt] = __builtin_amdgcn_mfma_f32_16x16x32_bf16(
                    a[mt], b[nt], acc[mt][nt], 0, 0, 0);
        __syncthreads();   // drains vmcnt(0): stage(t+1) done; reads of S[(t+1)&1] done
    }

    const bool is_root = (bn == 0);   // block-uniform
    #pragma unroll
    for (int mt = 0; mt < 4; ++mt) {
        #pragma unroll
        for (int nt = 0; nt < 4; ++nt) {
            int col = bn + wn + nt * 16 + fr;
            float bv = bias[col];
            #pragma unroll
            for (int r = 0; r < 4; ++r) {
                int row = bm + wm + mt * 16 + ((lane >> 4) << 2) + r;
                float v = acc[mt][nt][r] + bv;
                if (is_root) out_root[(size_t)row * 256 + col] = f2bf(v);
                else         out_msg[(size_t)row * 1024 + (col - 256)] = f2bf(v);
            }
        }
    }
}

// ---------------------------------------------------------------------------
// Mid-layer aggregation: per node, per relation, mean of h[src] -> agg.
// 1 wave per node, barrier-free; gathers from the 31 MB h buffer
// (L2/L3-resident -> ~3x faster than gathering from the 123 MB msg buffer).
// ---------------------------------------------------------------------------
__global__ __launch_bounds__(256) void gather_mean_h(
    const unsigned short* __restrict__ h,       // [M_PAD,256]
    const int* __restrict__ rp4, const int* __restrict__ e_srcs,
    const float* __restrict__ inv4,
    unsigned short* __restrict__ agg)           // [M_PAD,1024]
{
    int node = blockIdx.x * 4 + (threadIdx.x >> 6);
    if (node >= N_NODES) return;
    int lane = threadIdx.x & 63;
    float4 iv = *(const float4*)&inv4[(size_t)node * 4];

    #pragma unroll
    for (int r = 0; r < 4; ++r) {
        int lo = rp4[node * 4 + r], hi = rp4[node * 4 + r + 1];
        float4 s = make_float4(0.f, 0.f, 0.f, 0.f);
        for (int e = lo; e < hi; ++e) {
            int sidx = e_srcs[e];
            uint2 q = *(const uint2*)&h[(size_t)sidx * 256 + lane * 4];
            s.x += bflo(q.x); s.y += bfhi(q.x);
            s.z += bflo(q.y); s.w += bfhi(q.y);
        }
        float f = (r == 0) ? iv.x : (r == 1) ? iv.y : (r == 2) ? iv.z : iv.w;
        ushort4 o;
        o.x = f2bf(s.x * f); o.y = f2bf(s.y * f);
        o.z = f2bf(s.z * f); o.w = f2bf(s.w * f);
        *(ushort4*)&agg[(size_t)node * 1024 + r * 256 + lane * 4] = o;
    }
}

// ---------------------------------------------------------------------------
// Mid-layer GEMM, occupancy-fixed: out = relu([agg | h] @ W + b), K = 1280.
// Tile 64x256, 256 threads (4 waves x 64x64), grid 938 (~3.7 blocks/CU, LDS
// 40 KB -> 3-4 resident): cross-block wave overlap hides the barrier drains
// that throttled the 469-block 128x256 version.
// ---------------------------------------------------------------------------
__global__ __launch_bounds__(256) void gemm_mid(
    const unsigned short* __restrict__ agg,   // [M_PAD,1024]  (k < 1024)
    const unsigned short* __restrict__ hin,   // [M_PAD,256]   (k >= 1024)
    const unsigned short* __restrict__ Bt,    // W [256 n][1280 k]
    const float* __restrict__ bias,           // [256]
    unsigned short* __restrict__ h_out)       // [M_PAD,256]
{
    __shared__ __align__(16) unsigned short S[2][(64 + 256) * 32];    // 2 x 20480 B

    const int tid  = threadIdx.x;
    const int wave = tid >> 6, lane = tid & 63;
    const int bm   = blockIdx.x * 64;
    const int wcol = wave * 64;

    const int lr = lane >> 2;
    const int kg = ((lane & 3) ^ ((lr ^ (lr >> 2)) & 3)) * 8;

    // 20 staging groups (4 A rows-of-16 + 16 B rows-of-16), 5 per wave
    const unsigned short* srcA[5];   // agg base (A) or W base (B)
    const unsigned short* srcH[5];   // h base (A groups only)
    int ldoff[5];
    bool grpA[5];
    #pragma unroll
    for (int j = 0; j < 5; ++j) {
        int g = wave * 5 + j;
        if (g < 4) {
            grpA[j] = true;
            srcA[j] = agg + (size_t)(bm + g * 16 + lr) * 1024 + kg;
            srcH[j] = hin + (size_t)(bm + g * 16 + lr) * 256 + kg;
            ldoff[j] = g * 512;                       // As: shorts 0..2047
        } else {
            grpA[j] = false;
            srcA[j] = Bt + (size_t)((g - 4) * 16 + lr) * N_TOT + kg;
            srcH[j] = nullptr;
            ldoff[j] = 2048 + (g - 4) * 512;          // Bs: shorts 2048..10239
        }
    }

    f32x4 acc[4][4] = {};
    const int fr = lane & 15;
    const int qsw = (((lane >> 4) ^ fr ^ (fr >> 2)) & 3) * 8;

    auto stage = [&](int t, unsigned short* buf) {
        #pragma unroll
        for (int j = 0; j < 5; ++j) {
            const unsigned short* s;
            if (grpA[j]) s = (t < 32) ? srcA[j] + t * 32 : srcH[j] + (t - 32) * 32;
            else         s = srcA[j] + t * 32;
            gload16(s, buf + ldoff[j]);
        }
    };

    stage(0, S[0]);
    __syncthreads();

    #pragma unroll 1
    for (int t = 0; t < 40; ++t) {
        if (t + 1 < 40) stage(t + 1, S[(t + 1) & 1]);
        const unsigned short* cur = S[t & 1];
        short8 a[4], b[4];
        #pragma unroll
        for (int q = 0; q < 4; ++q) {
            a[q] = *(const short8*)&cur[(q * 16 + fr) * 32 + qsw];
            b[q] = *(const short8*)&cur[2048 + (wcol + q * 16 + fr) * 32 + qsw];
        }
        #pragma unroll
        for (int mt = 0; mt < 4; ++mt)
            #pragma unroll
            for (int nt = 0; nt < 4; ++nt)
                acc[mt][nt] = __builtin_amdgcn_mfma_f32_16x16x32_bf16(
                    a[mt], b[nt], acc[mt][nt], 0, 0, 0);
        __syncthreads();
    }

    #pragma unroll
    for (int mt = 0; mt < 4; ++mt) {
        #pragma unroll
        for (int nt = 0; nt < 4; ++nt) {
            int col = wcol + nt * 16 + fr;
            float bv = bias[col];
            #pragma unroll
            for (int r = 0; r < 4; ++r) {
                int row = bm + mt * 16 + ((lane >> 4) << 2) + r;
                float v = fmaxf(acc[mt][nt][r] + bv, 0.f);
                h_out[(size_t)row * 256 + col] = f2bf(v);
            }
        }
    }
}

// ---------------------------------------------------------------------------
// Prep kernels
// ---------------------------------------------------------------------------
__global__ void convert_x(const float* __restrict__ x, unsigned short* __restrict__ xb) {
    size_t i = ((size_t)blockIdx.x * 256 + threadIdx.x) * 4;
    if (i >= (size_t)M_PAD * D_IN) return;
    ushort4 o;
    if (i < (size_t)N_NODES * D_IN) {
        float4 v = *(const float4*)&x[i];
        o.x = f2bf(v.x); o.y = f2bf(v.y); o.z = f2bf(v.z); o.w = f2bf(v.w);
    } else {
        o.x = o.y = o.z = o.w = 0;
    }
    *(ushort4*)&xb[i] = o;
}

__global__ void pack_w0(const float* __restrict__ root0, const float* __restrict__ w0,
                        unsigned short* __restrict__ Wt0) {
    int idx = blockIdx.x * 256 + threadIdx.x;            // Wt0[n][k], [1280 x 768]
    if (idx >= N_TOT * D_IN) return;
    int k = idx % D_IN, n = idx / D_IN;
    float v = (n < 256) ? root0[k * 256 + n]
                        : w0[(((n >> 8) - 1) * D_IN + k) * 256 + (n & 255)];
    Wt0[idx] = f2bf(v);
}

// WtR[l][n][k], n in [0,256), k in [0,1280):
//   k<1024 -> w_rest[l][k>>8][k&255][n]; k>=1024 -> root_rest[l][k-1024][n]
__global__ void pack_wr(const float* __restrict__ root_rest, const float* __restrict__ w_rest,
                        unsigned short* __restrict__ WtR) {
    int idx = blockIdx.x * 256 + threadIdx.x;
    if (idx >= 5 * 256 * N_TOT) return;
    int k = idx % N_TOT; int t = idx / N_TOT; int n = t & 255; int l = t >> 8;
    float v = (k < 1024)
        ? w_rest[(((l * 4 + (k >> 8)) * 256) + (k & 255)) * 256 + n]
        : root_rest[(l * 256 + (k - 1024)) * 256 + n];
    WtR[idx] = f2bf(v);
}

__global__ void build_bias(const float* __restrict__ b0, float* __restrict__ eb) {
    int i = blockIdx.x * 256 + threadIdx.x;
    if (i < N_TOT) eb[i] = (i < 256) ? b0[i] : 0.f;
}

// ---------------------------------------------------------------------------
// (dst, rel)-sorted CSR over 4*N segments
// ---------------------------------------------------------------------------
__global__ void deg4_count(const int* __restrict__ dst, const int* __restrict__ rel,
                           int* __restrict__ deg4, int E) {
    int e = blockIdx.x * 256 + threadIdx.x;
    if (e < E) atomicAdd(&deg4[dst[e] * 4 + rel[e]], 1);
}

__global__ void invert4(const int* __restrict__ deg4, float* __restrict__ inv4, int n) {
    int i = blockIdx.x * 256 + threadIdx.x;
    if (i < n) inv4[i] = 1.0f / (float)max(deg4[i], 1);
}

__global__ __launch_bounds__(256) void block_sum(const int* __restrict__ deg,
                                                 int* __restrict__ bsum, int n) {
    __shared__ int s[256];
    int i = blockIdx.x * 256 + threadIdx.x;
    s[threadIdx.x] = (i < n) ? deg[i] : 0;
    __syncthreads();
    for (int o = 128; o > 0; o >>= 1) {
        if (threadIdx.x < o) s[threadIdx.x] += s[threadIdx.x + o];
        __syncthreads();
    }
    if (threadIdx.x == 0) bsum[blockIdx.x] = s[0];
}

__global__ __launch_bounds__(1024) void scan_bsum(const int* __restrict__ bsum,
                                                  int* __restrict__ boff, int nb) {
    __shared__ int s[1024];
    int t = threadIdx.x;
    int v0 = (t < nb) ? bsum[t] : 0;
    s[t] = v0;
    __syncthreads();
    for (int o = 1; o < 1024; o <<= 1) {
        int v = (t >= o) ? s[t - o] : 0;
        __syncthreads();
        s[t] += v;
        __syncthreads();
    }
    if (t < nb) boff[t] = s[t] - v0;   // exclusive
}

__global__ __launch_bounds__(256) void block_scan_write(
    const int* __restrict__ deg, const int* __restrict__ boff,
    int* __restrict__ row_ptr, int* __restrict__ cursor, int n, int total) {
    __shared__ int s[256];
    int t = threadIdx.x;
    int i = blockIdx.x * 256 + t;
    int v = (i < n) ? deg[i] : 0;
    s[t] = v;
    __syncthreads();
    for (int o = 1; o < 256; o <<= 1) {
        int u = (t >= o) ? s[t - o] : 0;
        __syncthreads();
        s[t] += u;
        __syncthreads();
    }
    int excl = s[t] - v + boff[blockIdx.x];
    if (i < n) { row_ptr[i] = excl; cursor[i] = excl; }
    if (blockIdx.x == 0 && t == 0) row_ptr[n] = total;
}

__global__ void place_edges4(const int* __restrict__ dst, const int* __restrict__ src,
                             const int* __restrict__ rel, int* __restrict__ cursor,
                             int* __restrict__ e_srcs, int E) {
    int e = blockIdx.x * 256 + threadIdx.x;
    if (e < E) {
        int p = atomicAdd(&cursor[dst[e] * 4 + rel[e]], 1);
        e_srcs[p] = src[e];
    }
}

// ---------------------------------------------------------------------------
// Layer-0 aggregate: h0 = relu(root[n] + sum_r inv_r * sum_e msg[src, r])
// ---------------------------------------------------------------------------
__global__ __launch_bounds__(256) void aggregate0(
    const unsigned short* __restrict__ rootb,   // [M_PAD,256]
    const unsigned short* __restrict__ msg,     // [M_PAD,1024]
    const int* __restrict__ rp4, const int* __restrict__ e_srcs,
    const float* __restrict__ inv4,
    unsigned short* __restrict__ h_out)         // [M_PAD,256]
{
    int node = blockIdx.x * 4 + (threadIdx.x >> 6);
    if (node >= N_NODES) return;
    int lane = threadIdx.x & 63;
    float4 iv = *(const float4*)&inv4[(size_t)node * 4];

    ushort4 rt = *(const ushort4*)&rootb[(size_t)node * 256 + lane * 4];
    float4 acc = make_float4(bf2f(rt.x), bf2f(rt.y), bf2f(rt.z), bf2f(rt.w));

    #pragma unroll
    for (int r = 0; r < 4; ++r) {
        int lo = rp4[(size_t)node * 4 + r], hi = rp4[(size_t)node * 4 + r + 1];
        float f = (r == 0) ? iv.x : (r == 1) ? iv.y : (r == 2) ? iv.z : iv.w;
        float4 s4 = make_float4(0, 0, 0, 0);
        for (int e = lo; e < hi; ++e) {
            int s = e_srcs[e];
            ushort4 m = *(const ushort4*)&msg[(size_t)s * 1024 + (r << 8) + lane * 4];
            s4.x += bf2f(m.x); s4.y += bf2f(m.y);
            s4.z += bf2f(m.z); s4.w += bf2f(m.w);
        }
        acc.x += s4.x * f; acc.y += s4.y * f;
        acc.z += s4.z * f; acc.w += s4.w * f;
    }
    ushort4 o;
    o.x = f2bf(fmaxf(acc.x, 0.f));
    o.y = f2bf(fmaxf(acc.y, 0.f));
    o.z = f2bf(fmaxf(acc.z, 0.f));
    o.w = f2bf(fmaxf(acc.w, 0.f));
    *(ushort4*)&h_out[(size_t)node * 256 + lane * 4] = o;
}

// ---------------------------------------------------------------------------
// Pooling + MLP head
// ---------------------------------------------------------------------------
__global__ __launch_bounds__(256) void pool_kernel(
    const unsigned short* __restrict__ h, const int* __restrict__ batch,
    float* __restrict__ g_feat)
{
    int g = blockIdx.x;
    int t = threadIdx.x;
    __shared__ int s_lo, s_hi;
    if (t == 0) {
        int lo = 0, hi = N_NODES;
        while (lo < hi) { int m = (lo + hi) >> 1; if (batch[m] < g) lo = m + 1; else hi = m; }
        s_lo = lo;
        int lo2 = lo, hi2 = N_NODES;
        while (lo2 < hi2) { int m = (lo2 + hi2) >> 1; if (batch[m] < g + 1) lo2 = m + 1; else hi2 = m; }
        s_hi = lo2;
    }
    __syncthreads();
    int lo = s_lo, hi = s_hi;
    float sum = 0.f, mx = 0.f;   // post-ReLU
    for (int n = lo; n < hi; ++n) {
        float v = bf2f(h[(size_t)n * 256 + t]);
        sum += v;
        mx = fmaxf(mx, v);
    }
    float cnt = (float)(hi - lo);
    g_feat[g * 512 + t]       = sum / fmaxf(cnt, 1.0f);
    g_feat[g * 512 + 256 + t] = (cnt > 0.f) ? mx : 0.f;
}

__global__ __launch_bounds__(128) void mlp_head(
    const float* __restrict__ g_feat,
    const float* __restrict__ fc1_w, const float* __restrict__ fc1_b,
    const float* __restrict__ fc2_w, const float* __restrict__ fc2_b,
    float* __restrict__ out)
{
    __shared__ float gf[512];
    __shared__ float partial[2];
    int g = blockIdx.x, t = threadIdx.x;
    for (int i = t; i < 512; i += 128) gf[i] = g_feat[g * 512 + i];
    __syncthreads();
    float acc = fc1_b[t];
    for (int i = 0; i < 512; ++i) acc += gf[i] * fc1_w[i * 128 + t];
    float h1 = fmaxf(acc, 0.f);
    float v = h1 * fc2_w[t];
    #pragma unroll
    for (int off = 32; off > 0; off >>= 1) v += __shfl_down(v, off);
    if ((t & 63) == 0) partial[t >> 6] = v;
    __syncthreads();
    if (t == 0) {
        float s = partial[0] + partial[1] + fc2_b[0];
        out[g] = 1.0f / (1.0f + expf(-s));
    }
}

// ---------------------------------------------------------------------------
// Launch
// ---------------------------------------------------------------------------
extern "C" void kernel_launch(void* const* d_in, const int* in_sizes, int n_in,
                              void* d_out, int out_size, void* d_ws, size_t ws_size,
                              hipStream_t stream) {
    const float* x          = (const float*)d_in[0];
    const int*   edge_index = (const int*)d_in[1];
    const int*   edge_attr  = (const int*)d_in[2];
    const int*   batch      = (const int*)d_in[3];
    const float* w0         = (const float*)d_in[4];
    const float* root0      = (const float*)d_in[5];
    const float* b0         = (const float*)d_in[6];
    const float* w_rest     = (const float*)d_in[7];
    const float* root_rest  = (const float*)d_in[8];
    const float* b_rest     = (const float*)d_in[9];
    const float* fc1_w      = (const float*)d_in[10];
    const float* fc1_b      = (const float*)d_in[11];
    const float* fc2_w      = (const float*)d_in[12];
    const float* fc2_b      = (const float*)d_in[13];
    float* out = (float*)d_out;

    const int* e_src = edge_index;
    const int* e_dst = edge_index + N_EDGES;

    char* p = (char*)d_ws;
    auto alloc = [&](size_t bytes) { char* q = p; p += (bytes + 255) & ~(size_t)255; return q; };
    unsigned short* x_bf   = (unsigned short*)alloc((size_t)M_PAD * D_IN * 2);   // 92 MB
    unsigned short* msgbuf = (unsigned short*)alloc((size_t)M_PAD * 1024 * 2);   // 123 MB (L0 msg, then agg)
    unsigned short* hA     = (unsigned short*)alloc((size_t)M_PAD * 256 * 2);    // 31 MB
    unsigned short* hB     = (unsigned short*)alloc((size_t)M_PAD * 256 * 2);    // 31 MB
    unsigned short* Wt0    = (unsigned short*)alloc((size_t)N_TOT * D_IN * 2);
    unsigned short* WtR    = (unsigned short*)alloc((size_t)5 * 256 * N_TOT * 2);
    float*          ebias  = (float*)alloc(N_TOT * 4);
    float*          inv4   = (float*)alloc((size_t)N_NODES * 4 * 4);
    float*          g_feat = (float*)alloc((size_t)N_GRAPHS * 512 * 4);
    int*            deg4   = (int*)alloc((size_t)N_NODES * 4 * 4);
    int*            rp4    = (int*)alloc(((size_t)N_NODES * 4 + 1) * 4);
    int*            cursor4= (int*)alloc((size_t)N_NODES * 4 * 4);
    int*            bsum   = (int*)alloc(1024 * 4);
    int*            boff   = (int*)alloc(1024 * 4);
    int*            e_srcs = (int*)alloc((size_t)N_EDGES * 4);

    const int n4 = N_NODES * 4;                 // 240000
    const int nscan4 = cdiv(n4, 256);           // 938

    // --- prep ---
    hipMemsetAsync(deg4, 0, (size_t)n4 * 4, stream);
    convert_x<<<cdiv(M_PAD * D_IN / 4, 256), 256, 0, stream>>>(x, x_bf);
    pack_w0<<<cdiv(N_TOT * D_IN, 256), 256, 0, stream>>>(root0, w0, Wt0);
    pack_wr<<<cdiv(5 * 256 * N_TOT, 256), 256, 0, stream>>>(root_rest, w_rest, WtR);
    build_bias<<<cdiv(N_TOT, 256), 256, 0, stream>>>(b0, ebias);
    deg4_count<<<cdiv(N_EDGES, 256), 256, 0, stream>>>(e_dst, edge_attr, deg4, N_EDGES);
    invert4<<<cdiv(n4, 256), 256, 0, stream>>>(deg4, inv4, n4);
    block_sum<<<nscan4, 256, 0, stream>>>(deg4, bsum, n4);
    scan_bsum<<<1, 1024, 0, stream>>>(bsum, boff, nscan4);
    block_scan_write<<<nscan4, 256, 0, stream>>>(deg4, boff, rp4, cursor4, n4, N_EDGES);
    place_edges4<<<cdiv(N_EDGES, 256), 256, 0, stream>>>(e_dst, e_src, edge_attr,
                                                         cursor4, e_srcs, N_EDGES);

    // --- layer 0: transform-first GEMM (K=768) + edge-parallel aggregate ---
    gemm_l0<<<8 * 295, 512, 0, stream>>>(x_bf, Wt0, ebias, hB, msgbuf, D_IN);
    aggregate0<<<cdiv(N_NODES, 4), 256, 0, stream>>>(hB, msgbuf, rp4, e_srcs, inv4, hA);

    // --- layers 1..5: aggregate-first (small-footprint gather) + 938-block GEMM ---
    unsigned short* cur = hA;
    unsigned short* nxt = hB;
    for (int L = 1; L < N_LAYERS; ++L) {
        gather_mean_h<<<cdiv(N_NODES, 4), 256, 0, stream>>>(cur, rp4, e_srcs, inv4, msgbuf);
        gemm_mid<<<M_PAD / 64, 256, 0, stream>>>(
            msgbuf, cur, WtR + (size_t)(L - 1) * 256 * N_TOT, b_rest + (size_t)(L - 1) * 256,
            nxt);
        unsigned short* t = cur; cur = nxt; nxt = t;
    }
    // final h in cur

    pool_kernel<<<N_GRAPHS, 256, 0, stream>>>(cur, batch, g_feat);
    mlp_head<<<N_GRAPHS, 128, 0, stream>>>(g_feat, fc1_w, fc1_b, fc2_w, fc2_b, out);
}

// Round 6
// 1252.429 us; speedup vs baseline: 1.0327x; 1.0327x over previous
//
#include <hip/hip_runtime.h>
#include <hip/hip_bf16.h>

#define N_NODES  60000
#define N_EDGES  240000
#define N_REL    4
#define N_GRAPHS 128
#define D_IN     768
#define D_H      256
#define N_LAYERS 6
#define M_PAD    60032            // 469 * 128
#define N_TOT    1280             // L0 out: 256 root + 4*256 msg; mid K: 1024 agg + 256 self

static inline int cdiv(int a, int b) { return (a + b - 1) / b; }

typedef __attribute__((ext_vector_type(8))) short short8;
typedef __attribute__((ext_vector_type(4))) float f32x4;

__device__ __forceinline__ float bf2f(unsigned short u) {
    union { unsigned int i; float f; } c; c.i = ((unsigned int)u) << 16; return c.f;
}
__device__ __forceinline__ float bflo(unsigned int u) {
    union { unsigned int i; float f; } c; c.i = u << 16; return c.f;
}
__device__ __forceinline__ float bfhi(unsigned int u) {
    union { unsigned int i; float f; } c; c.i = u & 0xffff0000u; return c.f;
}
__device__ __forceinline__ unsigned short f2bf(float f) {
    union { float f; unsigned int i; } c; c.f = f;
    unsigned int i = c.i;
    unsigned int r = (i + 0x7FFFu + ((i >> 16) & 1u)) >> 16;   // RNE
    return (unsigned short)r;
}

__device__ __forceinline__ void gload16(const void* g, void* l) {
    __builtin_amdgcn_global_load_lds((const __attribute__((address_space(1))) void*)g,
                                     (__attribute__((address_space(3))) void*)l, 16, 0, 0);
}

// ---------------------------------------------------------------------------
// Layer-0 GEMM (transform-first): A[M_PAD,768] bf16 @ Wt0[1280,768]^T.
// Double-buffered LDS; XCD-chunked tile remap (A row-panel L2 reuse).
// grid = 8 * 295 (15 tail blocks idle).
// ---------------------------------------------------------------------------
__global__ __launch_bounds__(512) void gemm_l0(
    const unsigned short* __restrict__ A,
    const unsigned short* __restrict__ Bt,
    const float* __restrict__ bias,
    unsigned short* __restrict__ out_root,
    unsigned short* __restrict__ out_msg,
    int K)
{
    __shared__ __align__(16) unsigned short S[2][(128 + 256) * 32];   // 2 x 24576 B

    const int bid  = blockIdx.x;
    const int xcd  = bid & 7;
    const int j    = bid >> 3;                       // 0..294
    const int nrow = (xcd < 5) ? 59 : 58;
    const int rbase = (xcd < 5) ? xcd * 59 : 295 + (xcd - 5) * 58;
    const int rr = j / 5, cc = j % 5;
    if (rr >= nrow) return;
    const int bm = (rbase + rr) * 128;
    const int bn = cc * 256;

    const int tid  = threadIdx.x;
    const int wave = tid >> 6, lane = tid & 63;
    const int wm = (wave & 1) * 64, wn = (wave >> 1) * 64;

    const int lr = lane >> 2;
    const int kg = ((lane & 3) ^ ((lr ^ (lr >> 2)) & 3)) * 8;   // swizzled k-chunk
    const unsigned short* gsrc[3];
    int ldoff[3];
    #pragma unroll
    for (int t = 0; t < 3; ++t) {
        int g = wave * 3 + t;
        if (g < 8) {
            gsrc[t] = A + (size_t)(bm + g * 16 + lr) * K + kg;
            ldoff[t] = g * 512;                       // As region: shorts 0..4095
        } else {
            gsrc[t] = Bt + (size_t)(bn + (g - 8) * 16 + lr) * K + kg;
            ldoff[t] = 4096 + (g - 8) * 512;          // Bs region: shorts 4096..12287
        }
    }

    f32x4 acc[4][4] = {};
    const int fr = lane & 15;
    const int qsw = (((lane >> 4) ^ fr ^ (fr >> 2)) & 3) * 8;

    const int nstep = K >> 5;                         // 24
    gload16(gsrc[0], S[0] + ldoff[0]);
    gload16(gsrc[1], S[0] + ldoff[1]);
    gload16(gsrc[2], S[0] + ldoff[2]);
    __syncthreads();                                  // slice 0 staged

    #pragma unroll 1
    for (int t = 0; t < nstep; ++t) {
        if (t + 1 < nstep) {                          // stage ahead into alt buffer
            unsigned short* nb = S[(t + 1) & 1];
            gload16(gsrc[0] + (t + 1) * 32, nb + ldoff[0]);
            gload16(gsrc[1] + (t + 1) * 32, nb + ldoff[1]);
            gload16(gsrc[2] + (t + 1) * 32, nb + ldoff[2]);
        }
        const unsigned short* cur = S[t & 1];
        short8 a[4], b[4];
        #pragma unroll
        for (int q = 0; q < 4; ++q) {
            a[q] = *(const short8*)&cur[(wm + q * 16 + fr) * 32 + qsw];
            b[q] = *(const short8*)&cur[4096 + (wn + q * 16 + fr) * 32 + qsw];
        }
        #pragma unroll
        for (int mt = 0; mt < 4; ++mt)
            #pragma unroll
            for (int nt = 0; nt < 4; ++nt)
                acc[mt][nt] = __builtin_amdgcn_mfma_f32_16x16x32_bf16(
                    a[mt], b[nt], acc[mt][nt], 0, 0, 0);
        __syncthreads();   // drains vmcnt(0): stage(t+1) done; reads of S[(t+1)&1] done
    }

    const bool is_root = (bn == 0);   // block-uniform
    #pragma unroll
    for (int mt = 0; mt < 4; ++mt) {
        #pragma unroll
        for (int nt = 0; nt < 4; ++nt) {
            int col = bn + wn + nt * 16 + fr;
            float bv = bias[col];
            #pragma unroll
            for (int r = 0; r < 4; ++r) {
                int row = bm + wm + mt * 16 + ((lane >> 4) << 2) + r;
                float v = acc[mt][nt][r] + bv;
                if (is_root) out_root[(size_t)row * 256 + col] = f2bf(v);
                else         out_msg[(size_t)row * 1024 + (col - 256)] = f2bf(v);
            }
        }
    }
}

// ---------------------------------------------------------------------------
// Mid-layer aggregation: per node, per relation, mean of h[src] -> agg.
// 1 wave per node, barrier-free; gathers from the 31 MB h buffer
// (L2/L3-resident); latency hidden by TLP (15000 blocks).
// ---------------------------------------------------------------------------
__global__ __launch_bounds__(256) void gather_mean_h(
    const unsigned short* __restrict__ h,       // [M_PAD,256]
    const int* __restrict__ rp4, const int* __restrict__ e_srcs,
    const float* __restrict__ inv4,
    unsigned short* __restrict__ agg)           // [M_PAD,1024]
{
    int node = blockIdx.x * 4 + (threadIdx.x >> 6);
    if (node >= N_NODES) return;
    int lane = threadIdx.x & 63;
    float4 iv = *(const float4*)&inv4[(size_t)node * 4];

    #pragma unroll
    for (int r = 0; r < 4; ++r) {
        int lo = rp4[node * 4 + r], hi = rp4[node * 4 + r + 1];
        float4 s = make_float4(0.f, 0.f, 0.f, 0.f);
        for (int e = lo; e < hi; ++e) {
            int sidx = e_srcs[e];
            uint2 q = *(const uint2*)&h[(size_t)sidx * 256 + lane * 4];
            s.x += bflo(q.x); s.y += bfhi(q.x);
            s.z += bflo(q.y); s.w += bfhi(q.y);
        }
        float f = (r == 0) ? iv.x : (r == 1) ? iv.y : (r == 2) ? iv.z : iv.w;
        ushort4 o;
        o.x = f2bf(s.x * f); o.y = f2bf(s.y * f);
        o.z = f2bf(s.z * f); o.w = f2bf(s.w * f);
        *(ushort4*)&agg[(size_t)node * 1024 + r * 256 + lane * 4] = o;
    }
}

// ---------------------------------------------------------------------------
// Mid-layer GEMM: out = relu([agg | h] @ W + b), K = 1280.
// Tile 128x128, 256 threads (4 waves x 64x64), grid 938 (469 rows x 2 cols).
// Per wave-K-step: 4 stage loads : 16 MFMA (vs 3:16 in gemm_l0); LDS 32 KB
// -> ~5 resident blocks/CU, ~3.7 queued: cross-block overlap hides barrier
// drains (the 469x512t version at 1.8 blocks/CU could not).
// Bijective XCD-chunked remap: both col-panels of a row-tile on one XCD.
// ---------------------------------------------------------------------------
__global__ __launch_bounds__(256) void gemm_layer(
    const unsigned short* __restrict__ agg,   // [M_PAD,1024]  (k < 1024)
    const unsigned short* __restrict__ hin,   // [M_PAD,256]   (k >= 1024)
    const unsigned short* __restrict__ Bt,    // W [256 n][1280 k]
    const float* __restrict__ bias,           // [256]
    unsigned short* __restrict__ h_out)       // [M_PAD,256]
{
    __shared__ __align__(16) unsigned short S[2][(128 + 128) * 32];   // 2 x 16384 B

    // bijective XCD-chunked remap over 938 tiles (dispatch: blockIdx%8 -> XCD)
    const int orig = blockIdx.x;
    const int xcd  = orig & 7;
    const int j    = orig >> 3;                 // 0..117 (xcd<2) / 0..116 (xcd>=2)
    const int wgid = (xcd < 2 ? xcd * 118 : 236 + (xcd - 2) * 117) + j;
    const int rr = wgid >> 1, cc = wgid & 1;    // row-tile, col-panel
    const int bm = rr * 128;
    const int bn = cc * 128;

    const int tid  = threadIdx.x;
    const int wave = tid >> 6, lane = tid & 63;
    const int wm = (wave & 1) * 64, wn = (wave >> 1) * 64;

    const int lr = lane >> 2;
    const int kg = ((lane & 3) ^ ((lr ^ (lr >> 2)) & 3)) * 8;

    // 16 staging groups (8 A rows-of-16 + 8 B rows-of-16), 4 per wave
    const unsigned short* srcA[4];
    const unsigned short* srcH[4];
    int ldoff[4];
    bool grpA[4];
    #pragma unroll
    for (int t = 0; t < 4; ++t) {
        int g = wave * 4 + t;
        if (g < 8) {
            grpA[t] = true;
            srcA[t] = agg + (size_t)(bm + g * 16 + lr) * 1024 + kg;
            srcH[t] = hin + (size_t)(bm + g * 16 + lr) * 256 + kg;
            ldoff[t] = g * 512;                       // As: shorts 0..4095
        } else {
            grpA[t] = false;
            srcA[t] = Bt + (size_t)(bn + (g - 8) * 16 + lr) * N_TOT + kg;
            srcH[t] = nullptr;
            ldoff[t] = 4096 + (g - 8) * 512;          // Bs: shorts 4096..8191
        }
    }

    f32x4 acc[4][4] = {};
    const int fr = lane & 15;
    const int qsw = (((lane >> 4) ^ fr ^ (fr >> 2)) & 3) * 8;

    auto stage = [&](int t, unsigned short* buf) {
        #pragma unroll
        for (int u = 0; u < 4; ++u) {
            const unsigned short* s;
            if (grpA[u]) s = (t < 32) ? srcA[u] + t * 32 : srcH[u] + (t - 32) * 32;
            else         s = srcA[u] + t * 32;
            gload16(s, buf + ldoff[u]);
        }
    };

    stage(0, S[0]);
    __syncthreads();

    #pragma unroll 1
    for (int t = 0; t < 40; ++t) {
        if (t + 1 < 40) stage(t + 1, S[(t + 1) & 1]);
        const unsigned short* cur = S[t & 1];
        short8 a[4], b[4];
        #pragma unroll
        for (int q = 0; q < 4; ++q) {
            a[q] = *(const short8*)&cur[(wm + q * 16 + fr) * 32 + qsw];
            b[q] = *(const short8*)&cur[4096 + (wn + q * 16 + fr) * 32 + qsw];
        }
        #pragma unroll
        for (int mt = 0; mt < 4; ++mt)
            #pragma unroll
            for (int nt = 0; nt < 4; ++nt)
                acc[mt][nt] = __builtin_amdgcn_mfma_f32_16x16x32_bf16(
                    a[mt], b[nt], acc[mt][nt], 0, 0, 0);
        __syncthreads();
    }

    #pragma unroll
    for (int mt = 0; mt < 4; ++mt) {
        #pragma unroll
        for (int nt = 0; nt < 4; ++nt) {
            int col = bn + wn + nt * 16 + fr;
            float bv = bias[col];
            #pragma unroll
            for (int r = 0; r < 4; ++r) {
                int row = bm + wm + mt * 16 + ((lane >> 4) << 2) + r;
                float v = fmaxf(acc[mt][nt][r] + bv, 0.f);
                h_out[(size_t)row * 256 + col] = f2bf(v);
            }
        }
    }
}

// ---------------------------------------------------------------------------
// Prep kernels
// ---------------------------------------------------------------------------
__global__ void convert_x(const float* __restrict__ x, unsigned short* __restrict__ xb) {
    size_t i = ((size_t)blockIdx.x * 256 + threadIdx.x) * 4;
    if (i >= (size_t)M_PAD * D_IN) return;
    ushort4 o;
    if (i < (size_t)N_NODES * D_IN) {
        float4 v = *(const float4*)&x[i];
        o.x = f2bf(v.x); o.y = f2bf(v.y); o.z = f2bf(v.z); o.w = f2bf(v.w);
    } else {
        o.x = o.y = o.z = o.w = 0;
    }
    *(ushort4*)&xb[i] = o;
}

__global__ void pack_w0(const float* __restrict__ root0, const float* __restrict__ w0,
                        unsigned short* __restrict__ Wt0) {
    int idx = blockIdx.x * 256 + threadIdx.x;            // Wt0[n][k], [1280 x 768]
    if (idx >= N_TOT * D_IN) return;
    int k = idx % D_IN, n = idx / D_IN;
    float v = (n < 256) ? root0[k * 256 + n]
                        : w0[(((n >> 8) - 1) * D_IN + k) * 256 + (n & 255)];
    Wt0[idx] = f2bf(v);
}

// WtR[l][n][k], n in [0,256), k in [0,1280):
//   k<1024 -> w_rest[l][k>>8][k&255][n]; k>=1024 -> root_rest[l][k-1024][n]
__global__ void pack_wr(const float* __restrict__ root_rest, const float* __restrict__ w_rest,
                        unsigned short* __restrict__ WtR) {
    int idx = blockIdx.x * 256 + threadIdx.x;
    if (idx >= 5 * 256 * N_TOT) return;
    int k = idx % N_TOT; int t = idx / N_TOT; int n = t & 255; int l = t >> 8;
    float v = (k < 1024)
        ? w_rest[(((l * 4 + (k >> 8)) * 256) + (k & 255)) * 256 + n]
        : root_rest[(l * 256 + (k - 1024)) * 256 + n];
    WtR[idx] = f2bf(v);
}

__global__ void build_bias(const float* __restrict__ b0, float* __restrict__ eb) {
    int i = blockIdx.x * 256 + threadIdx.x;
    if (i < N_TOT) eb[i] = (i < 256) ? b0[i] : 0.f;
}

// ---------------------------------------------------------------------------
// (dst, rel)-sorted CSR over 4*N segments
// ---------------------------------------------------------------------------
__global__ void deg4_count(const int* __restrict__ dst, const int* __restrict__ rel,
                           int* __restrict__ deg4, int E) {
    int e = blockIdx.x * 256 + threadIdx.x;
    if (e < E) atomicAdd(&deg4[dst[e] * 4 + rel[e]], 1);
}

__global__ void invert4(const int* __restrict__ deg4, float* __restrict__ inv4, int n) {
    int i = blockIdx.x * 256 + threadIdx.x;
    if (i < n) inv4[i] = 1.0f / (float)max(deg4[i], 1);
}

__global__ __launch_bounds__(256) void block_sum(const int* __restrict__ deg,
                                                 int* __restrict__ bsum, int n) {
    __shared__ int s[256];
    int i = blockIdx.x * 256 + threadIdx.x;
    s[threadIdx.x] = (i < n) ? deg[i] : 0;
    __syncthreads();
    for (int o = 128; o > 0; o >>= 1) {
        if (threadIdx.x < o) s[threadIdx.x] += s[threadIdx.x + o];
        __syncthreads();
    }
    if (threadIdx.x == 0) bsum[blockIdx.x] = s[0];
}

__global__ __launch_bounds__(1024) void scan_bsum(const int* __restrict__ bsum,
                                                  int* __restrict__ boff, int nb) {
    __shared__ int s[1024];
    int t = threadIdx.x;
    int v0 = (t < nb) ? bsum[t] : 0;
    s[t] = v0;
    __syncthreads();
    for (int o = 1; o < 1024; o <<= 1) {
        int v = (t >= o) ? s[t - o] : 0;
        __syncthreads();
        s[t] += v;
        __syncthreads();
    }
    if (t < nb) boff[t] = s[t] - v0;   // exclusive
}

__global__ __launch_bounds__(256) void block_scan_write(
    const int* __restrict__ deg, const int* __restrict__ boff,
    int* __restrict__ row_ptr, int* __restrict__ cursor, int n, int total) {
    __shared__ int s[256];
    int t = threadIdx.x;
    int i = blockIdx.x * 256 + t;
    int v = (i < n) ? deg[i] : 0;
    s[t] = v;
    __syncthreads();
    for (int o = 1; o < 256; o <<= 1) {
        int u = (t >= o) ? s[t - o] : 0;
        __syncthreads();
        s[t] += u;
        __syncthreads();
    }
    int excl = s[t] - v + boff[blockIdx.x];
    if (i < n) { row_ptr[i] = excl; cursor[i] = excl; }
    if (blockIdx.x == 0 && t == 0) row_ptr[n] = total;
}

__global__ void place_edges4(const int* __restrict__ dst, const int* __restrict__ src,
                             const int* __restrict__ rel, int* __restrict__ cursor,
                             int* __restrict__ e_srcs, int E) {
    int e = blockIdx.x * 256 + threadIdx.x;
    if (e < E) {
        int p = atomicAdd(&cursor[dst[e] * 4 + rel[e]], 1);
        e_srcs[p] = src[e];
    }
}

// ---------------------------------------------------------------------------
// Layer-0 aggregate: h0 = relu(root[n] + sum_r inv_r * sum_e msg[src, r])
// ---------------------------------------------------------------------------
__global__ __launch_bounds__(256) void aggregate0(
    const unsigned short* __restrict__ rootb,   // [M_PAD,256]
    const unsigned short* __restrict__ msg,     // [M_PAD,1024]
    const int* __restrict__ rp4, const int* __restrict__ e_srcs,
    const float* __restrict__ inv4,
    unsigned short* __restrict__ h_out)         // [M_PAD,256]
{
    int node = blockIdx.x * 4 + (threadIdx.x >> 6);
    if (node >= N_NODES) return;
    int lane = threadIdx.x & 63;
    float4 iv = *(const float4*)&inv4[(size_t)node * 4];

    ushort4 rt = *(const ushort4*)&rootb[(size_t)node * 256 + lane * 4];
    float4 acc = make_float4(bf2f(rt.x), bf2f(rt.y), bf2f(rt.z), bf2f(rt.w));

    #pragma unroll
    for (int r = 0; r < 4; ++r) {
        int lo = rp4[(size_t)node * 4 + r], hi = rp4[(size_t)node * 4 + r + 1];
        float f = (r == 0) ? iv.x : (r == 1) ? iv.y : (r == 2) ? iv.z : iv.w;
        float4 s4 = make_float4(0, 0, 0, 0);
        for (int e = lo; e < hi; ++e) {
            int s = e_srcs[e];
            ushort4 m = *(const ushort4*)&msg[(size_t)s * 1024 + (r << 8) + lane * 4];
            s4.x += bf2f(m.x); s4.y += bf2f(m.y);
            s4.z += bf2f(m.z); s4.w += bf2f(m.w);
        }
        acc.x += s4.x * f; acc.y += s4.y * f;
        acc.z += s4.z * f; acc.w += s4.w * f;
    }
    ushort4 o;
    o.x = f2bf(fmaxf(acc.x, 0.f));
    o.y = f2bf(fmaxf(acc.y, 0.f));
    o.z = f2bf(fmaxf(acc.z, 0.f));
    o.w = f2bf(fmaxf(acc.w, 0.f));
    *(ushort4*)&h_out[(size_t)node * 256 + lane * 4] = o;
}

// ---------------------------------------------------------------------------
// Pooling + MLP head
// ---------------------------------------------------------------------------
__global__ __launch_bounds__(256) void pool_kernel(
    const unsigned short* __restrict__ h, const int* __restrict__ batch,
    float* __restrict__ g_feat)
{
    int g = blockIdx.x;
    int t = threadIdx.x;
    __shared__ int s_lo, s_hi;
    if (t == 0) {
        int lo = 0, hi = N_NODES;
        while (lo < hi) { int m = (lo + hi) >> 1; if (batch[m] < g) lo = m + 1; else hi = m; }
        s_lo = lo;
        int lo2 = lo, hi2 = N_NODES;
        while (lo2 < hi2) { int m = (lo2 + hi2) >> 1; if (batch[m] < g + 1) lo2 = m + 1; else hi2 = m; }
        s_hi = lo2;
    }
    __syncthreads();
    int lo = s_lo, hi = s_hi;
    float sum = 0.f, mx = 0.f;   // post-ReLU
    for (int n = lo; n < hi; ++n) {
        float v = bf2f(h[(size_t)n * 256 + t]);
        sum += v;
        mx = fmaxf(mx, v);
    }
    float cnt = (float)(hi - lo);
    g_feat[g * 512 + t]       = sum / fmaxf(cnt, 1.0f);
    g_feat[g * 512 + 256 + t] = (cnt > 0.f) ? mx : 0.f;
}

__global__ __launch_bounds__(128) void mlp_head(
    const float* __restrict__ g_feat,
    const float* __restrict__ fc1_w, const float* __restrict__ fc1_b,
    const float* __restrict__ fc2_w, const float* __restrict__ fc2_b,
    float* __restrict__ out)
{
    __shared__ float gf[512];
    __shared__ float partial[2];
    int g = blockIdx.x, t = threadIdx.x;
    for (int i = t; i < 512; i += 128) gf[i] = g_feat[g * 512 + i];
    __syncthreads();
    float acc = fc1_b[t];
    for (int i = 0; i < 512; ++i) acc += gf[i] * fc1_w[i * 128 + t];
    float h1 = fmaxf(acc, 0.f);
    float v = h1 * fc2_w[t];
    #pragma unroll
    for (int off = 32; off > 0; off >>= 1) v += __shfl_down(v, off);
    if ((t & 63) == 0) partial[t >> 6] = v;
    __syncthreads();
    if (t == 0) {
        float s = partial[0] + partial[1] + fc2_b[0];
        out[g] = 1.0f / (1.0f + expf(-s));
    }
}

// ---------------------------------------------------------------------------
// Launch
// ---------------------------------------------------------------------------
extern "C" void kernel_launch(void* const* d_in, const int* in_sizes, int n_in,
                              void* d_out, int out_size, void* d_ws, size_t ws_size,
                              hipStream_t stream) {
    const float* x          = (const float*)d_in[0];
    const int*   edge_index = (const int*)d_in[1];
    const int*   edge_attr  = (const int*)d_in[2];
    const int*   batch      = (const int*)d_in[3];
    const float* w0         = (const float*)d_in[4];
    const float* root0      = (const float*)d_in[5];
    const float* b0         = (const float*)d_in[6];
    const float* w_rest     = (const float*)d_in[7];
    const float* root_rest  = (const float*)d_in[8];
    const float* b_rest     = (const float*)d_in[9];
    const float* fc1_w      = (const float*)d_in[10];
    const float* fc1_b      = (const float*)d_in[11];
    const float* fc2_w      = (const float*)d_in[12];
    const float* fc2_b      = (const float*)d_in[13];
    float* out = (float*)d_out;

    const int* e_src = edge_index;
    const int* e_dst = edge_index + N_EDGES;

    char* p = (char*)d_ws;
    auto alloc = [&](size_t bytes) { char* q = p; p += (bytes + 255) & ~(size_t)255; return q; };
    unsigned short* x_bf   = (unsigned short*)alloc((size_t)M_PAD * D_IN * 2);   // 92 MB
    unsigned short* msgbuf = (unsigned short*)alloc((size_t)M_PAD * 1024 * 2);   // 123 MB (L0 msg, then agg)
    unsigned short* hA     = (unsigned short*)alloc((size_t)M_PAD * 256 * 2);    // 31 MB
    unsigned short* hB     = (unsigned short*)alloc((size_t)M_PAD * 256 * 2);    // 31 MB
    unsigned short* Wt0    = (unsigned short*)alloc((size_t)N_TOT * D_IN * 2);
    unsigned short* WtR    = (unsigned short*)alloc((size_t)5 * 256 * N_TOT * 2);
    float*          ebias  = (float*)alloc(N_TOT * 4);
    float*          inv4   = (float*)alloc((size_t)N_NODES * 4 * 4);
    float*          g_feat = (float*)alloc((size_t)N_GRAPHS * 512 * 4);
    int*            deg4   = (int*)alloc((size_t)N_NODES * 4 * 4);
    int*            rp4    = (int*)alloc(((size_t)N_NODES * 4 + 1) * 4);
    int*            cursor4= (int*)alloc((size_t)N_NODES * 4 * 4);
    int*            bsum   = (int*)alloc(1024 * 4);
    int*            boff   = (int*)alloc(1024 * 4);
    int*            e_srcs = (int*)alloc((size_t)N_EDGES * 4);

    const int n4 = N_NODES * 4;                 // 240000
    const int nscan4 = cdiv(n4, 256);           // 938

    // --- prep ---
    hipMemsetAsync(deg4, 0, (size_t)n4 * 4, stream);
    convert_x<<<cdiv(M_PAD * D_IN / 4, 256), 256, 0, stream>>>(x, x_bf);
    pack_w0<<<cdiv(N_TOT * D_IN, 256), 256, 0, stream>>>(root0, w0, Wt0);
    pack_wr<<<cdiv(5 * 256 * N_TOT, 256), 256, 0, stream>>>(root_rest, w_rest, WtR);
    build_bias<<<cdiv(N_TOT, 256), 256, 0, stream>>>(b0, ebias);
    deg4_count<<<cdiv(N_EDGES, 256), 256, 0, stream>>>(e_dst, edge_attr, deg4, N_EDGES);
    invert4<<<cdiv(n4, 256), 256, 0, stream>>>(deg4, inv4, n4);
    block_sum<<<nscan4, 256, 0, stream>>>(deg4, bsum, n4);
    scan_bsum<<<1, 1024, 0, stream>>>(bsum, boff, nscan4);
    block_scan_write<<<nscan4, 256, 0, stream>>>(deg4, boff, rp4, cursor4, n4, N_EDGES);
    place_edges4<<<cdiv(N_EDGES, 256), 256, 0, stream>>>(e_dst, e_src, edge_attr,
                                                         cursor4, e_srcs, N_EDGES);

    // --- layer 0: transform-first GEMM (K=768) + edge-parallel aggregate ---
    gemm_l0<<<8 * 295, 512, 0, stream>>>(x_bf, Wt0, ebias, hB, msgbuf, D_IN);
    aggregate0<<<cdiv(N_NODES, 4), 256, 0, stream>>>(hB, msgbuf, rp4, e_srcs, inv4, hA);

    // --- layers 1..5: aggregate-first gather + 938-block 128x128 GEMM ---
    unsigned short* cur = hA;
    unsigned short* nxt = hB;
    for (int L = 1; L < N_LAYERS; ++L) {
        gather_mean_h<<<cdiv(N_NODES, 4), 256, 0, stream>>>(cur, rp4, e_srcs, inv4, msgbuf);
        gemm_layer<<<938, 256, 0, stream>>>(
            msgbuf, cur, WtR + (size_t)(L - 1) * 256 * N_TOT, b_rest + (size_t)(L - 1) * 256,
            nxt);
        unsigned short* t = cur; cur = nxt; nxt = t;
    }
    // final h in cur

    pool_kernel<<<N_GRAPHS, 256, 0, stream>>>(cur, batch, g_feat);
    mlp_head<<<N_GRAPHS, 128, 0, stream>>>(g_feat, fc1_w, fc1_b, fc2_w, fc2_b, out);
}

// Round 8
// 1251.161 us; speedup vs baseline: 1.0338x; 1.0010x over previous
//
#include <hip/hip_runtime.h>
#include <hip/hip_bf16.h>

#define N_NODES  60000
#define N_EDGES  240000
#define N_REL    4
#define N_GRAPHS 128
#define D_IN     768
#define D_H      256
#define N_LAYERS 6
#define M_PAD    60160            // 235 * 256
#define N_TOT    1280             // L0 out: 256 root + 4*256 msg; mid K: 1024 agg + 256 self

static inline int cdiv(int a, int b) { return (a + b - 1) / b; }

typedef __attribute__((ext_vector_type(8))) short short8;
typedef __attribute__((ext_vector_type(4))) float f32x4;

__device__ __forceinline__ float bf2f(unsigned short u) {
    union { unsigned int i; float f; } c; c.i = ((unsigned int)u) << 16; return c.f;
}
__device__ __forceinline__ float bflo(unsigned int u) {
    union { unsigned int i; float f; } c; c.i = u << 16; return c.f;
}
__device__ __forceinline__ float bfhi(unsigned int u) {
    union { unsigned int i; float f; } c; c.i = u & 0xffff0000u; return c.f;
}
__device__ __forceinline__ unsigned short f2bf(float f) {
    union { float f; unsigned int i; } c; c.f = f;
    unsigned int i = c.i;
    unsigned int r = (i + 0x7FFFu + ((i >> 16) & 1u)) >> 16;   // RNE
    return (unsigned short)r;
}

__device__ __forceinline__ void gload16(const void* g, void* l) {
    __builtin_amdgcn_global_load_lds((const __attribute__((address_space(1))) void*)g,
                                     (__attribute__((address_space(3))) void*)l, 16, 0, 0);
}

// ---------------------------------------------------------------------------
// Layer-0 GEMM, 256x256 tile: A[M_PAD,768] bf16 @ Wt0[1280,768]^T.
// 8 waves (2Mx4N), wave tile 128x64, acc[8][4].  Staged bytes vs the old
// 128x256 tile: 880 MB vs 1320 MB (the kernels are staging-BW-bound at
// ~8.4 TB/s L2->LDS).  Double-buffered LDS (64 KB), bijective XCD remap so
// the 5 col-panels of a row land on one XCD.  grid = 8*147 (1 idle).
// ---------------------------------------------------------------------------
__global__ __launch_bounds__(512) void gemm_l0(
    const unsigned short* __restrict__ A,
    const unsigned short* __restrict__ Bt,
    const float* __restrict__ bias,
    unsigned short* __restrict__ out_root,
    unsigned short* __restrict__ out_msg,
    int K)
{
    __shared__ __align__(16) unsigned short S[2][(256 + 256) * 32];   // 2 x 32768 B

    // bijective remap over 1175 tiles: xcd<7 -> 147 blocks, xcd=7 -> 146
    const int bid = blockIdx.x;
    const int xcd = bid & 7;
    const int j   = bid >> 3;
    if (xcd == 7 && j >= 146) return;
    const int wgid = (xcd < 7) ? xcd * 147 + j : 1029 + j;   // 0..1174
    const int rr = wgid / 5, cc = wgid % 5;
    const int bm = rr * 256;
    const int bn = cc * 256;

    const int tid  = threadIdx.x;
    const int wave = tid >> 6, lane = tid & 63;
    const int wm = (wave >> 2) * 128, wn = (wave & 3) * 64;

    const int lr = lane >> 2;
    const int kg = ((lane & 3) ^ ((lr ^ (lr >> 2)) & 3)) * 8;   // swizzled k-chunk

    // 32 staging groups (16 A + 16 B), 4 per wave
    const unsigned short* gsrc[4];
    int ldoff[4];
    #pragma unroll
    for (int t = 0; t < 4; ++t) {
        int g = wave * 4 + t;
        if (g < 16) {
            gsrc[t] = A + (size_t)(bm + g * 16 + lr) * K + kg;
            ldoff[t] = g * 512;                        // As: shorts 0..8191
        } else {
            gsrc[t] = Bt + (size_t)(bn + (g - 16) * 16 + lr) * K + kg;
            ldoff[t] = 8192 + (g - 16) * 512;          // Bs: shorts 8192..16383
        }
    }

    f32x4 acc[8][4] = {};
    const int fr = lane & 15;
    const int qsw = (((lane >> 4) ^ fr ^ (fr >> 2)) & 3) * 8;

    const int nstep = K >> 5;                          // 24
    gload16(gsrc[0], S[0] + ldoff[0]);
    gload16(gsrc[1], S[0] + ldoff[1]);
    gload16(gsrc[2], S[0] + ldoff[2]);
    gload16(gsrc[3], S[0] + ldoff[3]);
    __syncthreads();

    #pragma unroll 1
    for (int t = 0; t < nstep; ++t) {
        if (t + 1 < nstep) {
            unsigned short* nb = S[(t + 1) & 1];
            gload16(gsrc[0] + (t + 1) * 32, nb + ldoff[0]);
            gload16(gsrc[1] + (t + 1) * 32, nb + ldoff[1]);
            gload16(gsrc[2] + (t + 1) * 32, nb + ldoff[2]);
            gload16(gsrc[3] + (t + 1) * 32, nb + ldoff[3]);
        }
        const unsigned short* cur = S[t & 1];
        short8 a[8], b[4];
        #pragma unroll
        for (int q = 0; q < 8; ++q)
            a[q] = *(const short8*)&cur[(wm + q * 16 + fr) * 32 + qsw];
        #pragma unroll
        for (int nt = 0; nt < 4; ++nt)
            b[nt] = *(const short8*)&cur[8192 + (wn + nt * 16 + fr) * 32 + qsw];
        #pragma unroll
        for (int mt = 0; mt < 8; ++mt)
            #pragma unroll
            for (int nt = 0; nt < 4; ++nt)
                acc[mt][nt] = __builtin_amdgcn_mfma_f32_16x16x32_bf16(
                    a[mt], b[nt], acc[mt][nt], 0, 0, 0);
        __syncthreads();
    }

    const bool is_root = (bn == 0);
    #pragma unroll
    for (int mt = 0; mt < 8; ++mt) {
        #pragma unroll
        for (int nt = 0; nt < 4; ++nt) {
            int col = bn + wn + nt * 16 + fr;
            float bv = bias[col];
            #pragma unroll
            for (int r = 0; r < 4; ++r) {
                int row = bm + wm + mt * 16 + ((lane >> 4) << 2) + r;
                float v = acc[mt][nt][r] + bv;
                if (is_root) out_root[(size_t)row * 256 + col] = f2bf(v);
                else         out_msg[(size_t)row * 1024 + (col - 256)] = f2bf(v);
            }
        }
    }
}

// ---------------------------------------------------------------------------
// Mid-layer GEMM, 256x256 tile: out = relu([agg | h] @ W + b), K = 1280.
// grid = 235 (whole grid resident in one pass); B staged 235x640KB = 150 MB
// (vs 300 MB at 128-row tiles) + A once 154 MB.  In-block double-buffer
// hides the per-step drain.
// ---------------------------------------------------------------------------
__global__ __launch_bounds__(512) void gemm_mid(
    const unsigned short* __restrict__ agg,   // [M_PAD,1024]  (k < 1024)
    const unsigned short* __restrict__ hin,   // [M_PAD,256]   (k >= 1024)
    const unsigned short* __restrict__ Bt,    // W [256 n][1280 k]
    const float* __restrict__ bias,           // [256]
    unsigned short* __restrict__ h_out)       // [M_PAD,256]
{
    __shared__ __align__(16) unsigned short S[2][(256 + 256) * 32];   // 2 x 32768 B

    const int bm = blockIdx.x * 256;

    const int tid  = threadIdx.x;
    const int wave = tid >> 6, lane = tid & 63;
    const int wm = (wave >> 2) * 128, wn = (wave & 3) * 64;

    const int lr = lane >> 2;
    const int kg = ((lane & 3) ^ ((lr ^ (lr >> 2)) & 3)) * 8;

    const unsigned short* srcA[4];
    const unsigned short* srcH[4];
    int ldoff[4];
    bool grpA[4];
    #pragma unroll
    for (int t = 0; t < 4; ++t) {
        int g = wave * 4 + t;
        if (g < 16) {
            grpA[t] = true;
            srcA[t] = agg + (size_t)(bm + g * 16 + lr) * 1024 + kg;
            srcH[t] = hin + (size_t)(bm + g * 16 + lr) * 256 + kg;
            ldoff[t] = g * 512;
        } else {
            grpA[t] = false;
            srcA[t] = Bt + (size_t)((g - 16) * 16 + lr) * N_TOT + kg;
            srcH[t] = nullptr;
            ldoff[t] = 8192 + (g - 16) * 512;
        }
    }

    f32x4 acc[8][4] = {};
    const int fr = lane & 15;
    const int qsw = (((lane >> 4) ^ fr ^ (fr >> 2)) & 3) * 8;

    auto stage = [&](int t, unsigned short* buf) {
        #pragma unroll
        for (int u = 0; u < 4; ++u) {
            const unsigned short* s;
            if (grpA[u]) s = (t < 32) ? srcA[u] + t * 32 : srcH[u] + (t - 32) * 32;
            else         s = srcA[u] + t * 32;
            gload16(s, buf + ldoff[u]);
        }
    };

    stage(0, S[0]);
    __syncthreads();

    #pragma unroll 1
    for (int t = 0; t < 40; ++t) {
        if (t + 1 < 40) stage(t + 1, S[(t + 1) & 1]);
        const unsigned short* cur = S[t & 1];
        short8 a[8], b[4];
        #pragma unroll
        for (int q = 0; q < 8; ++q)
            a[q] = *(const short8*)&cur[(wm + q * 16 + fr) * 32 + qsw];
        #pragma unroll
        for (int nt = 0; nt < 4; ++nt)
            b[nt] = *(const short8*)&cur[8192 + (wn + nt * 16 + fr) * 32 + qsw];
        #pragma unroll
        for (int mt = 0; mt < 8; ++mt)
            #pragma unroll
            for (int nt = 0; nt < 4; ++nt)
                acc[mt][nt] = __builtin_amdgcn_mfma_f32_16x16x32_bf16(
                    a[mt], b[nt], acc[mt][nt], 0, 0, 0);
        __syncthreads();
    }

    #pragma unroll
    for (int mt = 0; mt < 8; ++mt) {
        #pragma unroll
        for (int nt = 0; nt < 4; ++nt) {
            int col = wn + nt * 16 + fr;
            float bv = bias[col];
            #pragma unroll
            for (int r = 0; r < 4; ++r) {
                int row = bm + wm + mt * 16 + ((lane >> 4) << 2) + r;
                float v = fmaxf(acc[mt][nt][r] + bv, 0.f);
                h_out[(size_t)row * 256 + col] = f2bf(v);
            }
        }
    }
}

// ---------------------------------------------------------------------------
// Mid-layer aggregation: per node, per relation, mean of h[src] -> agg.
// 1 wave per node, barrier-free; gathers from the 31 MB h buffer.
// ---------------------------------------------------------------------------
__global__ __launch_bounds__(256) void gather_mean_h(
    const unsigned short* __restrict__ h,       // [M_PAD,256]
    const int* __restrict__ rp4, const int* __restrict__ e_srcs,
    const float* __restrict__ inv4,
    unsigned short* __restrict__ agg)           // [M_PAD,1024]
{
    int node = blockIdx.x * 4 + (threadIdx.x >> 6);
    if (node >= N_NODES) return;
    int lane = threadIdx.x & 63;
    float4 iv = *(const float4*)&inv4[(size_t)node * 4];

    #pragma unroll
    for (int r = 0; r < 4; ++r) {
        int lo = rp4[node * 4 + r], hi = rp4[node * 4 + r + 1];
        float4 s = make_float4(0.f, 0.f, 0.f, 0.f);
        for (int e = lo; e < hi; ++e) {
            int sidx = e_srcs[e];
            uint2 q = *(const uint2*)&h[(size_t)sidx * 256 + lane * 4];
            s.x += bflo(q.x); s.y += bfhi(q.x);
            s.z += bflo(q.y); s.w += bfhi(q.y);
        }
        float f = (r == 0) ? iv.x : (r == 1) ? iv.y : (r == 2) ? iv.z : iv.w;
        ushort4 o;
        o.x = f2bf(s.x * f); o.y = f2bf(s.y * f);
        o.z = f2bf(s.z * f); o.w = f2bf(s.w * f);
        *(ushort4*)&agg[(size_t)node * 1024 + r * 256 + lane * 4] = o;
    }
}

// ---------------------------------------------------------------------------
// Prep kernels
// ---------------------------------------------------------------------------
__global__ void convert_x(const float* __restrict__ x, unsigned short* __restrict__ xb) {
    size_t i = ((size_t)blockIdx.x * 256 + threadIdx.x) * 4;
    if (i >= (size_t)M_PAD * D_IN) return;
    ushort4 o;
    if (i < (size_t)N_NODES * D_IN) {
        float4 v = *(const float4*)&x[i];
        o.x = f2bf(v.x); o.y = f2bf(v.y); o.z = f2bf(v.z); o.w = f2bf(v.w);
    } else {
        o.x = o.y = o.z = o.w = 0;
    }
    *(ushort4*)&xb[i] = o;
}

__global__ void pack_w0(const float* __restrict__ root0, const float* __restrict__ w0,
                        unsigned short* __restrict__ Wt0) {
    int idx = blockIdx.x * 256 + threadIdx.x;            // Wt0[n][k], [1280 x 768]
    if (idx >= N_TOT * D_IN) return;
    int k = idx % D_IN, n = idx / D_IN;
    float v = (n < 256) ? root0[k * 256 + n]
                        : w0[(((n >> 8) - 1) * D_IN + k) * 256 + (n & 255)];
    Wt0[idx] = f2bf(v);
}

// WtR[l][n][k], n in [0,256), k in [0,1280):
//   k<1024 -> w_rest[l][k>>8][k&255][n]; k>=1024 -> root_rest[l][k-1024][n]
__global__ void pack_wr(const float* __restrict__ root_rest, const float* __restrict__ w_rest,
                        unsigned short* __restrict__ WtR) {
    int idx = blockIdx.x * 256 + threadIdx.x;
    if (idx >= 5 * 256 * N_TOT) return;
    int k = idx % N_TOT; int t = idx / N_TOT; int n = t & 255; int l = t >> 8;
    float v = (k < 1024)
        ? w_rest[(((l * 4 + (k >> 8)) * 256) + (k & 255)) * 256 + n]
        : root_rest[(l * 256 + (k - 1024)) * 256 + n];
    WtR[idx] = f2bf(v);
}

__global__ void build_bias(const float* __restrict__ b0, float* __restrict__ eb) {
    int i = blockIdx.x * 256 + threadIdx.x;
    if (i < N_TOT) eb[i] = (i < 256) ? b0[i] : 0.f;
}

// ---------------------------------------------------------------------------
// (dst, rel)-sorted CSR over 4*N segments
// ---------------------------------------------------------------------------
__global__ void deg4_count(const int* __restrict__ dst, const int* __restrict__ rel,
                           int* __restrict__ deg4, int E) {
    int e = blockIdx.x * 256 + threadIdx.x;
    if (e < E) atomicAdd(&deg4[dst[e] * 4 + rel[e]], 1);
}

__global__ void invert4(const int* __restrict__ deg4, float* __restrict__ inv4, int n) {
    int i = blockIdx.x * 256 + threadIdx.x;
    if (i < n) inv4[i] = 1.0f / (float)max(deg4[i], 1);
}

__global__ __launch_bounds__(256) void block_sum(const int* __restrict__ deg,
                                                 int* __restrict__ bsum, int n) {
    __shared__ int s[256];
    int i = blockIdx.x * 256 + threadIdx.x;
    s[threadIdx.x] = (i < n) ? deg[i] : 0;
    __syncthreads();
    for (int o = 128; o > 0; o >>= 1) {
        if (threadIdx.x < o) s[threadIdx.x] += s[threadIdx.x + o];
        __syncthreads();
    }
    if (threadIdx.x == 0) bsum[blockIdx.x] = s[0];
}

__global__ __launch_bounds__(1024) void scan_bsum(const int* __restrict__ bsum,
                                                  int* __restrict__ boff, int nb) {
    __shared__ int s[1024];
    int t = threadIdx.x;
    int v0 = (t < nb) ? bsum[t] : 0;
    s[t] = v0;
    __syncthreads();
    for (int o = 1; o < 1024; o <<= 1) {
        int v = (t >= o) ? s[t - o] : 0;
        __syncthreads();
        s[t] += v;
        __syncthreads();
    }
    if (t < nb) boff[t] = s[t] - v0;   // exclusive
}

__global__ __launch_bounds__(256) void block_scan_write(
    const int* __restrict__ deg, const int* __restrict__ boff,
    int* __restrict__ row_ptr, int* __restrict__ cursor, int n, int total) {
    __shared__ int s[256];
    int t = threadIdx.x;
    int i = blockIdx.x * 256 + t;
    int v = (i < n) ? deg[i] : 0;
    s[t] = v;
    __syncthreads();
    for (int o = 1; o < 256; o <<= 1) {
        int u = (t >= o) ? s[t - o] : 0;
        __syncthreads();
        s[t] += u;
        __syncthreads();
    }
    int excl = s[t] - v + boff[blockIdx.x];
    if (i < n) { row_ptr[i] = excl; cursor[i] = excl; }
    if (blockIdx.x == 0 && t == 0) row_ptr[n] = total;
}

__global__ void place_edges4(const int* __restrict__ dst, const int* __restrict__ src,
                             const int* __restrict__ rel, int* __restrict__ cursor,
                             int* __restrict__ e_srcs, int E) {
    int e = blockIdx.x * 256 + threadIdx.x;
    if (e < E) {
        int p = atomicAdd(&cursor[dst[e] * 4 + rel[e]], 1);
        e_srcs[p] = src[e];
    }
}

// ---------------------------------------------------------------------------
// Layer-0 aggregate: h0 = relu(root[n] + sum_r inv_r * sum_e msg[src, r])
// ---------------------------------------------------------------------------
__global__ __launch_bounds__(256) void aggregate0(
    const unsigned short* __restrict__ rootb,   // [M_PAD,256]
    const unsigned short* __restrict__ msg,     // [M_PAD,1024]
    const int* __restrict__ rp4, const int* __restrict__ e_srcs,
    const float* __restrict__ inv4,
    unsigned short* __restrict__ h_out)         // [M_PAD,256]
{
    int node = blockIdx.x * 4 + (threadIdx.x >> 6);
    if (node >= N_NODES) return;
    int lane = threadIdx.x & 63;
    float4 iv = *(const float4*)&inv4[(size_t)node * 4];

    ushort4 rt = *(const ushort4*)&rootb[(size_t)node * 256 + lane * 4];
    float4 acc = make_float4(bf2f(rt.x), bf2f(rt.y), bf2f(rt.z), bf2f(rt.w));

    #pragma unroll
    for (int r = 0; r < 4; ++r) {
        int lo = rp4[(size_t)node * 4 + r], hi = rp4[(size_t)node * 4 + r + 1];
        float f = (r == 0) ? iv.x : (r == 1) ? iv.y : (r == 2) ? iv.z : iv.w;
        float4 s4 = make_float4(0, 0, 0, 0);
        for (int e = lo; e < hi; ++e) {
            int s = e_srcs[e];
            ushort4 m = *(const ushort4*)&msg[(size_t)s * 1024 + (r << 8) + lane * 4];
            s4.x += bf2f(m.x); s4.y += bf2f(m.y);
            s4.z += bf2f(m.z); s4.w += bf2f(m.w);
        }
        acc.x += s4.x * f; acc.y += s4.y * f;
        acc.z += s4.z * f; acc.w += s4.w * f;
    }
    ushort4 o;
    o.x = f2bf(fmaxf(acc.x, 0.f));
    o.y = f2bf(fmaxf(acc.y, 0.f));
    o.z = f2bf(fmaxf(acc.z, 0.f));
    o.w = f2bf(fmaxf(acc.w, 0.f));
    *(ushort4*)&h_out[(size_t)node * 256 + lane * 4] = o;
}

// ---------------------------------------------------------------------------
// Pooling + MLP head
// ---------------------------------------------------------------------------
__global__ __launch_bounds__(256) void pool_kernel(
    const unsigned short* __restrict__ h, const int* __restrict__ batch,
    float* __restrict__ g_feat)
{
    int g = blockIdx.x;
    int t = threadIdx.x;
    __shared__ int s_lo, s_hi;
    if (t == 0) {
        int lo = 0, hi = N_NODES;
        while (lo < hi) { int m = (lo + hi) >> 1; if (batch[m] < g) lo = m + 1; else hi = m; }
        s_lo = lo;
        int lo2 = lo, hi2 = N_NODES;
        while (lo2 < hi2) { int m = (lo2 + hi2) >> 1; if (batch[m] < g + 1) lo2 = m + 1; else hi2 = m; }
        s_hi = lo2;
    }
    __syncthreads();
    int lo = s_lo, hi = s_hi;
    float sum = 0.f, mx = 0.f;   // post-ReLU
    for (int n = lo; n < hi; ++n) {
        float v = bf2f(h[(size_t)n * 256 + t]);
        sum += v;
        mx = fmaxf(mx, v);
    }
    float cnt = (float)(hi - lo);
    g_feat[g * 512 + t]       = sum / fmaxf(cnt, 1.0f);
    g_feat[g * 512 + 256 + t] = (cnt > 0.f) ? mx : 0.f;
}

__global__ __launch_bounds__(128) void mlp_head(
    const float* __restrict__ g_feat,
    const float* __restrict__ fc1_w, const float* __restrict__ fc1_b,
    const float* __restrict__ fc2_w, const float* __restrict__ fc2_b,
    float* __restrict__ out)
{
    __shared__ float gf[512];
    __shared__ float partial[2];
    int g = blockIdx.x, t = threadIdx.x;
    for (int i = t; i < 512; i += 128) gf[i] = g_feat[g * 512 + i];
    __syncthreads();
    float acc = fc1_b[t];
    for (int i = 0; i < 512; ++i) acc += gf[i] * fc1_w[i * 128 + t];
    float h1 = fmaxf(acc, 0.f);
    float v = h1 * fc2_w[t];
    #pragma unroll
    for (int off = 32; off > 0; off >>= 1) v += __shfl_down(v, off);
    if ((t & 63) == 0) partial[t >> 6] = v;
    __syncthreads();
    if (t == 0) {
        float s = partial[0] + partial[1] + fc2_b[0];
        out[g] = 1.0f / (1.0f + expf(-s));
    }
}

// ---------------------------------------------------------------------------
// Launch
// ---------------------------------------------------------------------------
extern "C" void kernel_launch(void* const* d_in, const int* in_sizes, int n_in,
                              void* d_out, int out_size, void* d_ws, size_t ws_size,
                              hipStream_t stream) {
    const float* x          = (const float*)d_in[0];
    const int*   edge_index = (const int*)d_in[1];
    const int*   edge_attr  = (const int*)d_in[2];
    const int*   batch      = (const int*)d_in[3];
    const float* w0         = (const float*)d_in[4];
    const float* root0      = (const float*)d_in[5];
    const float* b0         = (const float*)d_in[6];
    const float* w_rest     = (const float*)d_in[7];
    const float* root_rest  = (const float*)d_in[8];
    const float* b_rest     = (const float*)d_in[9];
    const float* fc1_w      = (const float*)d_in[10];
    const float* fc1_b      = (const float*)d_in[11];
    const float* fc2_w      = (const float*)d_in[12];
    const float* fc2_b      = (const float*)d_in[13];
    float* out = (float*)d_out;

    const int* e_src = edge_index;
    const int* e_dst = edge_index + N_EDGES;

    char* p = (char*)d_ws;
    auto alloc = [&](size_t bytes) { char* q = p; p += (bytes + 255) & ~(size_t)255; return q; };
    unsigned short* x_bf   = (unsigned short*)alloc((size_t)M_PAD * D_IN * 2);   // 92 MB
    unsigned short* msgbuf = (unsigned short*)alloc((size_t)M_PAD * 1024 * 2);   // 123 MB (L0 msg, then agg)
    unsigned short* hA     = (unsigned short*)alloc((size_t)M_PAD * 256 * 2);    // 31 MB
    unsigned short* hB     = (unsigned short*)alloc((size_t)M_PAD * 256 * 2);    // 31 MB
    unsigned short* Wt0    = (unsigned short*)alloc((size_t)N_TOT * D_IN * 2);
    unsigned short* WtR    = (unsigned short*)alloc((size_t)5 * 256 * N_TOT * 2);
    float*          ebias  = (float*)alloc(N_TOT * 4);
    float*          inv4   = (float*)alloc((size_t)N_NODES * 4 * 4);
    float*          g_feat = (float*)alloc((size_t)N_GRAPHS * 512 * 4);
    int*            deg4   = (int*)alloc((size_t)N_NODES * 4 * 4);
    int*            rp4    = (int*)alloc(((size_t)N_NODES * 4 + 1) * 4);
    int*            cursor4= (int*)alloc((size_t)N_NODES * 4 * 4);
    int*            bsum   = (int*)alloc(1024 * 4);
    int*            boff   = (int*)alloc(1024 * 4);
    int*            e_srcs = (int*)alloc((size_t)N_EDGES * 4);

    const int n4 = N_NODES * 4;                 // 240000
    const int nscan4 = cdiv(n4, 256);           // 938

    // --- prep ---
    hipMemsetAsync(deg4, 0, (size_t)n4 * 4, stream);
    convert_x<<<cdiv(M_PAD * D_IN / 4, 256), 256, 0, stream>>>(x, x_bf);
    pack_w0<<<cdiv(N_TOT * D_IN, 256), 256, 0, stream>>>(root0, w0, Wt0);
    pack_wr<<<cdiv(5 * 256 * N_TOT, 256), 256, 0, stream>>>(root_rest, w_rest, WtR);
    build_bias<<<cdiv(N_TOT, 256), 256, 0, stream>>>(b0, ebias);
    deg4_count<<<cdiv(N_EDGES, 256), 256, 0, stream>>>(e_dst, edge_attr, deg4, N_EDGES);
    invert4<<<cdiv(n4, 256), 256, 0, stream>>>(deg4, inv4, n4);
    block_sum<<<nscan4, 256, 0, stream>>>(deg4, bsum, n4);
    scan_bsum<<<1, 1024, 0, stream>>>(bsum, boff, nscan4);
    block_scan_write<<<nscan4, 256, 0, stream>>>(deg4, boff, rp4, cursor4, n4, N_EDGES);
    place_edges4<<<cdiv(N_EDGES, 256), 256, 0, stream>>>(e_dst, e_src, edge_attr,
                                                         cursor4, e_srcs, N_EDGES);

    // --- layer 0: transform-first 256x256 GEMM (K=768) + edge-parallel aggregate ---
    gemm_l0<<<8 * 147, 512, 0, stream>>>(x_bf, Wt0, ebias, hB, msgbuf, D_IN);
    aggregate0<<<cdiv(N_NODES, 4), 256, 0, stream>>>(hB, msgbuf, rp4, e_srcs, inv4, hA);

    // --- layers 1..5: aggregate-first gather + 235-block 256x256 GEMM ---
    unsigned short* cur = hA;
    unsigned short* nxt = hB;
    for (int L = 1; L < N_LAYERS; ++L) {
        gather_mean_h<<<cdiv(N_NODES, 4), 256, 0, stream>>>(cur, rp4, e_srcs, inv4, msgbuf);
        gemm_mid<<<235, 512, 0, stream>>>(
            msgbuf, cur, WtR + (size_t)(L - 1) * 256 * N_TOT, b_rest + (size_t)(L - 1) * 256,
            nxt);
        unsigned short* t = cur; cur = nxt; nxt = t;
    }
    // final h in cur

    pool_kernel<<<N_GRAPHS, 256, 0, stream>>>(cur, batch, g_feat);
    mlp_head<<<N_GRAPHS, 128, 0, stream>>>(g_feat, fc1_w, fc1_b, fc2_w, fc2_b, out);
}

// Round 9
// 1192.848 us; speedup vs baseline: 1.0843x; 1.0489x over previous
//
#include <hip/hip_runtime.h>
#include <hip/hip_bf16.h>

#define N_NODES  60000
#define N_EDGES  240000
#define N_REL    4
#define N_GRAPHS 128
#define D_IN     768
#define D_H      256
#define N_LAYERS 6
#define M_PAD    60032            // 469 * 128
#define N_TOT    1280             // GEMM out: 256 root + 4*256 per-relation msg

static inline int cdiv(int a, int b) { return (a + b - 1) / b; }

typedef __attribute__((ext_vector_type(8))) short short8;
typedef __attribute__((ext_vector_type(4))) float f32x4;

__device__ __forceinline__ float bf2f(unsigned short u) {
    union { unsigned int i; float f; } c; c.i = ((unsigned int)u) << 16; return c.f;
}
__device__ __forceinline__ float bflo(unsigned int u) {
    union { unsigned int i; float f; } c; c.i = u << 16; return c.f;
}
__device__ __forceinline__ float bfhi(unsigned int u) {
    union { unsigned int i; float f; } c; c.i = u & 0xffff0000u; return c.f;
}
__device__ __forceinline__ unsigned short f2bf(float f) {
    union { float f; unsigned int i; } c; c.f = f;
    unsigned int i = c.i;
    unsigned int r = (i + 0x7FFFu + ((i >> 16) & 1u)) >> 16;   // RNE
    return (unsigned short)r;
}

__device__ __forceinline__ void gload16(const void* g, void* l) {
    __builtin_amdgcn_global_load_lds((const __attribute__((address_space(1))) void*)g,
                                     (__attribute__((address_space(3))) void*)l, 16, 0, 0);
}

// ---------------------------------------------------------------------------
// Transform GEMM (proven 128x256 tile, 157 us @ K=768, ~750 TF):
// A[M_PAD,K] bf16 @ Wt[1280,K]^T -> root[M,256] (+bias) and per-relation
// msg SLABS msg[r][M,256] (slab layout keeps the aggregate's gather
// footprint at 31 MB per phase instead of 123 MB uniform).
// Double-buffered LDS; XCD-chunked remap.  grid = 8*295 (15 idle).
// Used with K=768 (layer 0, A=x) and K=256 (mid layers, A=h; mean
// commutes with the per-relation linear map).
// ---------------------------------------------------------------------------
__global__ __launch_bounds__(512) void gemm_l0(
    const unsigned short* __restrict__ A,
    const unsigned short* __restrict__ Bt,
    const float* __restrict__ bias,
    unsigned short* __restrict__ out_root,
    unsigned short* __restrict__ out_msg,     // [4][M_PAD][256] slabs
    int K)
{
    __shared__ __align__(16) unsigned short S[2][(128 + 256) * 32];   // 2 x 24576 B

    const int bid  = blockIdx.x;
    const int xcd  = bid & 7;
    const int j    = bid >> 3;                       // 0..294
    const int nrow = (xcd < 5) ? 59 : 58;
    const int rbase = (xcd < 5) ? xcd * 59 : 295 + (xcd - 5) * 58;
    const int rr = j / 5, cc = j % 5;
    if (rr >= nrow) return;
    const int bm = (rbase + rr) * 128;
    const int bn = cc * 256;

    const int tid  = threadIdx.x;
    const int wave = tid >> 6, lane = tid & 63;
    const int wm = (wave & 1) * 64, wn = (wave >> 1) * 64;

    const int lr = lane >> 2;
    const int kg = ((lane & 3) ^ ((lr ^ (lr >> 2)) & 3)) * 8;   // swizzled k-chunk
    const unsigned short* gsrc[3];
    int ldoff[3];
    #pragma unroll
    for (int t = 0; t < 3; ++t) {
        int g = wave * 3 + t;
        if (g < 8) {
            gsrc[t] = A + (size_t)(bm + g * 16 + lr) * K + kg;
            ldoff[t] = g * 512;                       // As region: shorts 0..4095
        } else {
            gsrc[t] = Bt + (size_t)(bn + (g - 8) * 16 + lr) * K + kg;
            ldoff[t] = 4096 + (g - 8) * 512;          // Bs region: shorts 4096..12287
        }
    }

    f32x4 acc[4][4] = {};
    const int fr = lane & 15;
    const int qsw = (((lane >> 4) ^ fr ^ (fr >> 2)) & 3) * 8;

    const int nstep = K >> 5;                         // 24 (L0) or 8 (mid)
    gload16(gsrc[0], S[0] + ldoff[0]);
    gload16(gsrc[1], S[0] + ldoff[1]);
    gload16(gsrc[2], S[0] + ldoff[2]);
    __syncthreads();                                  // slice 0 staged

    #pragma unroll 1
    for (int t = 0; t < nstep; ++t) {
        if (t + 1 < nstep) {                          // stage ahead into alt buffer
            unsigned short* nb = S[(t + 1) & 1];
            gload16(gsrc[0] + (t + 1) * 32, nb + ldoff[0]);
            gload16(gsrc[1] + (t + 1) * 32, nb + ldoff[1]);
            gload16(gsrc[2] + (t + 1) * 32, nb + ldoff[2]);
        }
        const unsigned short* cur = S[t & 1];
        short8 a[4], b[4];
        #pragma unroll
        for (int q = 0; q < 4; ++q) {
            a[q] = *(const short8*)&cur[(wm + q * 16 + fr) * 32 + qsw];
            b[q] = *(const short8*)&cur[4096 + (wn + q * 16 + fr) * 32 + qsw];
        }
        #pragma unroll
        for (int mt = 0; mt < 4; ++mt)
            #pragma unroll
            for (int nt = 0; nt < 4; ++nt)
                acc[mt][nt] = __builtin_amdgcn_mfma_f32_16x16x32_bf16(
                    a[mt], b[nt], acc[mt][nt], 0, 0, 0);
        __syncthreads();   // drains vmcnt(0): stage(t+1) done; reads of S[(t+1)&1] done
    }

    const bool is_root = (bn == 0);   // block-uniform
    #pragma unroll
    for (int mt = 0; mt < 4; ++mt) {
        #pragma unroll
        for (int nt = 0; nt < 4; ++nt) {
            int col = bn + wn + nt * 16 + fr;
            float bv = bias[col];
            #pragma unroll
            for (int r = 0; r < 4; ++r) {
                int row = bm + wm + mt * 16 + ((lane >> 4) << 2) + r;
                float v = acc[mt][nt][r] + bv;
                if (is_root) {
                    out_root[(size_t)row * 256 + col] = f2bf(v);
                } else {
                    int plane = (col >> 8) - 1;                    // relation 0..3
                    out_msg[((size_t)plane * M_PAD + row) * 256 + (col & 255)] = f2bf(v);
                }
            }
        }
    }
}

// ---------------------------------------------------------------------------
// Prep kernels
// ---------------------------------------------------------------------------
__global__ void convert_x(const float* __restrict__ x, unsigned short* __restrict__ xb) {
    size_t i = ((size_t)blockIdx.x * 256 + threadIdx.x) * 4;
    if (i >= (size_t)M_PAD * D_IN) return;
    ushort4 o;
    if (i < (size_t)N_NODES * D_IN) {
        float4 v = *(const float4*)&x[i];
        o.x = f2bf(v.x); o.y = f2bf(v.y); o.z = f2bf(v.z); o.w = f2bf(v.w);
    } else {
        o.x = o.y = o.z = o.w = 0;
    }
    *(ushort4*)&xb[i] = o;
}

__global__ void pack_w0(const float* __restrict__ root0, const float* __restrict__ w0,
                        unsigned short* __restrict__ Wt0) {
    int idx = blockIdx.x * 256 + threadIdx.x;            // Wt0[n][k], [1280 x 768]
    if (idx >= N_TOT * D_IN) return;
    int k = idx % D_IN, n = idx / D_IN;
    float v = (n < 256) ? root0[k * 256 + n]
                        : w0[(((n >> 8) - 1) * D_IN + k) * 256 + (n & 255)];
    Wt0[idx] = f2bf(v);
}

// WtR[l][n][k], n in [0,1280), k in [0,256):
//   n<256  -> root_rest[l][k][n]
//   n>=256 -> w_rest[l][(n>>8)-1][k][n&255]
__global__ void pack_wr(const float* __restrict__ root_rest, const float* __restrict__ w_rest,
                        unsigned short* __restrict__ WtR) {
    int idx = blockIdx.x * 256 + threadIdx.x;
    if (idx >= 5 * N_TOT * 256) return;
    int k = idx & 255; int t = idx >> 8; int n = t % N_TOT; int l = t / N_TOT;
    float v = (n < 256)
        ? root_rest[(l * 256 + k) * 256 + n]
        : w_rest[(((l * 4 + ((n >> 8) - 1)) * 256) + k) * 256 + (n & 255)];
    WtR[idx] = f2bf(v);
}

// eb[6][1280]: l=0 -> [b0 | 0...]; l>=1 -> [b_rest[l-1] | 0...]
__global__ void build_bias_all(const float* __restrict__ b0, const float* __restrict__ b_rest,
                               float* __restrict__ eb) {
    int i = blockIdx.x * 256 + threadIdx.x;
    if (i >= 6 * N_TOT) return;
    int l = i / N_TOT, c = i % N_TOT;
    float v = 0.f;
    if (c < 256) v = (l == 0) ? b0[c] : b_rest[(l - 1) * 256 + c];
    eb[i] = v;
}

// ---------------------------------------------------------------------------
// (dst, rel)-sorted CSR over 4*N segments
// ---------------------------------------------------------------------------
__global__ void deg4_count(const int* __restrict__ dst, const int* __restrict__ rel,
                           int* __restrict__ deg4, int E) {
    int e = blockIdx.x * 256 + threadIdx.x;
    if (e < E) atomicAdd(&deg4[dst[e] * 4 + rel[e]], 1);
}

__global__ void invert4(const int* __restrict__ deg4, float* __restrict__ inv4, int n) {
    int i = blockIdx.x * 256 + threadIdx.x;
    if (i < n) inv4[i] = 1.0f / (float)max(deg4[i], 1);
}

__global__ __launch_bounds__(256) void block_sum(const int* __restrict__ deg,
                                                 int* __restrict__ bsum, int n) {
    __shared__ int s[256];
    int i = blockIdx.x * 256 + threadIdx.x;
    s[threadIdx.x] = (i < n) ? deg[i] : 0;
    __syncthreads();
    for (int o = 128; o > 0; o >>= 1) {
        if (threadIdx.x < o) s[threadIdx.x] += s[threadIdx.x + o];
        __syncthreads();
    }
    if (threadIdx.x == 0) bsum[blockIdx.x] = s[0];
}

__global__ __launch_bounds__(1024) void scan_bsum(const int* __restrict__ bsum,
                                                  int* __restrict__ boff, int nb) {
    __shared__ int s[1024];
    int t = threadIdx.x;
    int v0 = (t < nb) ? bsum[t] : 0;
    s[t] = v0;
    __syncthreads();
    for (int o = 1; o < 1024; o <<= 1) {
        int v = (t >= o) ? s[t - o] : 0;
        __syncthreads();
        s[t] += v;
        __syncthreads();
    }
    if (t < nb) boff[t] = s[t] - v0;   // exclusive
}

__global__ __launch_bounds__(256) void block_scan_write(
    const int* __restrict__ deg, const int* __restrict__ boff,
    int* __restrict__ row_ptr, int* __restrict__ cursor, int n, int total) {
    __shared__ int s[256];
    int t = threadIdx.x;
    int i = blockIdx.x * 256 + t;
    int v = (i < n) ? deg[i] : 0;
    s[t] = v;
    __syncthreads();
    for (int o = 1; o < 256; o <<= 1) {
        int u = (t >= o) ? s[t - o] : 0;
        __syncthreads();
        s[t] += u;
        __syncthreads();
    }
    int excl = s[t] - v + boff[blockIdx.x];
    if (i < n) { row_ptr[i] = excl; cursor[i] = excl; }
    if (blockIdx.x == 0 && t == 0) row_ptr[n] = total;
}

__global__ void place_edges4(const int* __restrict__ dst, const int* __restrict__ src,
                             const int* __restrict__ rel, int* __restrict__ cursor,
                             int* __restrict__ e_srcs, int E) {
    int e = blockIdx.x * 256 + threadIdx.x;
    if (e < E) {
        int p = atomicAdd(&cursor[dst[e] * 4 + rel[e]], 1);
        e_srcs[p] = src[e];
    }
}

// ---------------------------------------------------------------------------
// Aggregate (all layers): h_out = relu(root[n] + sum_r inv_r * sum_e msg_r[src])
// msg in per-relation SLABS [r][M_PAD][256]: each r-phase gathers within a
// 31 MB footprint (L2-friendly) instead of 123 MB uniform.
// 1 wave per node, barrier-free; latency hidden by TLP.
// ---------------------------------------------------------------------------
__global__ __launch_bounds__(256) void aggregate0(
    const unsigned short* __restrict__ rootb,   // [M_PAD,256]
    const unsigned short* __restrict__ msg,     // [4][M_PAD,256] slabs
    const int* __restrict__ rp4, const int* __restrict__ e_srcs,
    const float* __restrict__ inv4,
    unsigned short* __restrict__ h_out)         // [M_PAD,256]
{
    int node = blockIdx.x * 4 + (threadIdx.x >> 6);
    if (node >= N_NODES) return;
    int lane = threadIdx.x & 63;
    float4 iv = *(const float4*)&inv4[(size_t)node * 4];

    ushort4 rt = *(const ushort4*)&rootb[(size_t)node * 256 + lane * 4];
    float4 acc = make_float4(bf2f(rt.x), bf2f(rt.y), bf2f(rt.z), bf2f(rt.w));

    #pragma unroll
    for (int r = 0; r < 4; ++r) {
        int lo = rp4[(size_t)node * 4 + r], hi = rp4[(size_t)node * 4 + r + 1];
        float f = (r == 0) ? iv.x : (r == 1) ? iv.y : (r == 2) ? iv.z : iv.w;
        const unsigned short* slab = msg + (size_t)r * M_PAD * 256;
        float4 s4 = make_float4(0, 0, 0, 0);
        for (int e = lo; e < hi; ++e) {
            int s = e_srcs[e];
            ushort4 m = *(const ushort4*)&slab[(size_t)s * 256 + lane * 4];
            s4.x += bf2f(m.x); s4.y += bf2f(m.y);
            s4.z += bf2f(m.z); s4.w += bf2f(m.w);
        }
        acc.x += s4.x * f; acc.y += s4.y * f;
        acc.z += s4.z * f; acc.w += s4.w * f;
    }
    ushort4 o;
    o.x = f2bf(fmaxf(acc.x, 0.f));
    o.y = f2bf(fmaxf(acc.y, 0.f));
    o.z = f2bf(fmaxf(acc.z, 0.f));
    o.w = f2bf(fmaxf(acc.w, 0.f));
    *(ushort4*)&h_out[(size_t)node * 256 + lane * 4] = o;
}

// ---------------------------------------------------------------------------
// Pooling + MLP head
// ---------------------------------------------------------------------------
__global__ __launch_bounds__(256) void pool_kernel(
    const unsigned short* __restrict__ h, const int* __restrict__ batch,
    float* __restrict__ g_feat)
{
    int g = blockIdx.x;
    int t = threadIdx.x;
    __shared__ int s_lo, s_hi;
    if (t == 0) {
        int lo = 0, hi = N_NODES;
        while (lo < hi) { int m = (lo + hi) >> 1; if (batch[m] < g) lo = m + 1; else hi = m; }
        s_lo = lo;
        int lo2 = lo, hi2 = N_NODES;
        while (lo2 < hi2) { int m = (lo2 + hi2) >> 1; if (batch[m] < g + 1) lo2 = m + 1; else hi2 = m; }
        s_hi = lo2;
    }
    __syncthreads();
    int lo = s_lo, hi = s_hi;
    float sum = 0.f, mx = 0.f;   // post-ReLU
    for (int n = lo; n < hi; ++n) {
        float v = bf2f(h[(size_t)n * 256 + t]);
        sum += v;
        mx = fmaxf(mx, v);
    }
    float cnt = (float)(hi - lo);
    g_feat[g * 512 + t]       = sum / fmaxf(cnt, 1.0f);
    g_feat[g * 512 + 256 + t] = (cnt > 0.f) ? mx : 0.f;
}

__global__ __launch_bounds__(128) void mlp_head(
    const float* __restrict__ g_feat,
    const float* __restrict__ fc1_w, const float* __restrict__ fc1_b,
    const float* __restrict__ fc2_w, const float* __restrict__ fc2_b,
    float* __restrict__ out)
{
    __shared__ float gf[512];
    __shared__ float partial[2];
    int g = blockIdx.x, t = threadIdx.x;
    for (int i = t; i < 512; i += 128) gf[i] = g_feat[g * 512 + i];
    __syncthreads();
    float acc = fc1_b[t];
    for (int i = 0; i < 512; ++i) acc += gf[i] * fc1_w[i * 128 + t];
    float h1 = fmaxf(acc, 0.f);
    float v = h1 * fc2_w[t];
    #pragma unroll
    for (int off = 32; off > 0; off >>= 1) v += __shfl_down(v, off);
    if ((t & 63) == 0) partial[t >> 6] = v;
    __syncthreads();
    if (t == 0) {
        float s = partial[0] + partial[1] + fc2_b[0];
        out[g] = 1.0f / (1.0f + expf(-s));
    }
}

// ---------------------------------------------------------------------------
// Launch
// ---------------------------------------------------------------------------
extern "C" void kernel_launch(void* const* d_in, const int* in_sizes, int n_in,
                              void* d_out, int out_size, void* d_ws, size_t ws_size,
                              hipStream_t stream) {
    const float* x          = (const float*)d_in[0];
    const int*   edge_index = (const int*)d_in[1];
    const int*   edge_attr  = (const int*)d_in[2];
    const int*   batch      = (const int*)d_in[3];
    const float* w0         = (const float*)d_in[4];
    const float* root0      = (const float*)d_in[5];
    const float* b0         = (const float*)d_in[6];
    const float* w_rest     = (const float*)d_in[7];
    const float* root_rest  = (const float*)d_in[8];
    const float* b_rest     = (const float*)d_in[9];
    const float* fc1_w      = (const float*)d_in[10];
    const float* fc1_b      = (const float*)d_in[11];
    const float* fc2_w      = (const float*)d_in[12];
    const float* fc2_b      = (const float*)d_in[13];
    float* out = (float*)d_out;

    const int* e_src = edge_index;
    const int* e_dst = edge_index + N_EDGES;

    char* p = (char*)d_ws;
    auto alloc = [&](size_t bytes) { char* q = p; p += (bytes + 255) & ~(size_t)255; return q; };
    unsigned short* x_bf   = (unsigned short*)alloc((size_t)M_PAD * D_IN * 2);   // 92 MB; reused as rootT after L0
    unsigned short* msgbuf = (unsigned short*)alloc((size_t)M_PAD * 1024 * 2);   // 123 MB (4 slabs of 31 MB)
    unsigned short* hA     = (unsigned short*)alloc((size_t)M_PAD * 256 * 2);    // 31 MB
    unsigned short* hB     = (unsigned short*)alloc((size_t)M_PAD * 256 * 2);    // 31 MB
    unsigned short* Wt0    = (unsigned short*)alloc((size_t)N_TOT * D_IN * 2);
    unsigned short* WtR    = (unsigned short*)alloc((size_t)5 * N_TOT * 256 * 2);
    float*          ebias  = (float*)alloc((size_t)6 * N_TOT * 4);
    float*          inv4   = (float*)alloc((size_t)N_NODES * 4 * 4);
    float*          g_feat = (float*)alloc((size_t)N_GRAPHS * 512 * 4);
    int*            deg4   = (int*)alloc((size_t)N_NODES * 4 * 4);
    int*            rp4    = (int*)alloc(((size_t)N_NODES * 4 + 1) * 4);
    int*            cursor4= (int*)alloc((size_t)N_NODES * 4 * 4);
    int*            bsum   = (int*)alloc(1024 * 4);
    int*            boff   = (int*)alloc(1024 * 4);
    int*            e_srcs = (int*)alloc((size_t)N_EDGES * 4);

    const int n4 = N_NODES * 4;                 // 240000
    const int nscan4 = cdiv(n4, 256);           // 938

    // --- prep ---
    hipMemsetAsync(deg4, 0, (size_t)n4 * 4, stream);
    convert_x<<<cdiv(M_PAD * D_IN / 4, 256), 256, 0, stream>>>(x, x_bf);
    pack_w0<<<cdiv(N_TOT * D_IN, 256), 256, 0, stream>>>(root0, w0, Wt0);
    pack_wr<<<cdiv(5 * N_TOT * 256, 256), 256, 0, stream>>>(root_rest, w_rest, WtR);
    build_bias_all<<<cdiv(6 * N_TOT, 256), 256, 0, stream>>>(b0, b_rest, ebias);
    deg4_count<<<cdiv(N_EDGES, 256), 256, 0, stream>>>(e_dst, edge_attr, deg4, N_EDGES);
    invert4<<<cdiv(n4, 256), 256, 0, stream>>>(deg4, inv4, n4);
    block_sum<<<nscan4, 256, 0, stream>>>(deg4, bsum, n4);
    scan_bsum<<<1, 1024, 0, stream>>>(bsum, boff, nscan4);
    block_scan_write<<<nscan4, 256, 0, stream>>>(deg4, boff, rp4, cursor4, n4, N_EDGES);
    place_edges4<<<cdiv(N_EDGES, 256), 256, 0, stream>>>(e_dst, e_src, edge_attr,
                                                         cursor4, e_srcs, N_EDGES);

    // --- layer 0: transform-first GEMM (K=768) + slab aggregate ---
    gemm_l0<<<8 * 295, 512, 0, stream>>>(x_bf, Wt0, ebias, hB, msgbuf, D_IN);
    aggregate0<<<cdiv(N_NODES, 4), 256, 0, stream>>>(hB, msgbuf, rp4, e_srcs, inv4, hA);

    // --- layers 1..5: transform-first (K=256, well-shaped 2345-block GEMM)
    //     + slab aggregate.  mean(h)@W == mean(h@W).  rootT reuses x_bf. ---
    unsigned short* rootT = x_bf;
    unsigned short* cur = hA;
    unsigned short* nxt = hB;
    for (int L = 1; L < N_LAYERS; ++L) {
        gemm_l0<<<8 * 295, 512, 0, stream>>>(
            cur, WtR + (size_t)(L - 1) * N_TOT * 256, ebias + (size_t)L * N_TOT,
            rootT, msgbuf, 256);
        aggregate0<<<cdiv(N_NODES, 4), 256, 0, stream>>>(rootT, msgbuf, rp4, e_srcs, inv4, nxt);
        unsigned short* t = cur; cur = nxt; nxt = t;
    }
    // final h in cur

    pool_kernel<<<N_GRAPHS, 256, 0, stream>>>(cur, batch, g_feat);
    mlp_head<<<N_GRAPHS, 128, 0, stream>>>(g_feat, fc1_w, fc1_b, fc2_w, fc2_b, out);
}